// Round 4
// baseline (522.315 us; speedup 1.0000x reference)
//
#include <hip/hip_runtime.h>
#include <stdint.h>

typedef unsigned short u16;
typedef __bf16 bf16t;
typedef bf16t bf16x8 __attribute__((ext_vector_type(8)));
typedef float f32x4 __attribute__((ext_vector_type(4)));

#define DEV static __device__ __forceinline__

DEV u16 f2b(float f) {
  unsigned u = __float_as_uint(f);
  return (u16)((u + 0x7fffu + ((u >> 16) & 1u)) >> 16);
}
DEV float b2f(u16 h) { return __uint_as_float(((unsigned)h) << 16); }
DEV f32x4 fzero() { f32x4 v = {0.f, 0.f, 0.f, 0.f}; return v; }
DEV f32x4 mfma16(bf16x8 a, bf16x8 b, f32x4 c) {
  return __builtin_amdgcn_mfma_f32_16x16x32_bf16(a, b, c, 0, 0, 0);
}
DEV float exp2fast(float x) { return __builtin_amdgcn_exp2f(x); }  // v_exp_f32

// Problem constants
#define SEQ 1024
#define MEML 1024
#define BB 4
#define HH 1024
#define NHH 16
#define HDD 64
#define TOT 2048

// ------------------------- elementwise converts -------------------------

__global__ __launch_bounds__(256) void k_pack(const float* __restrict__ mem,
                                              const float* __restrict__ x,
                                              u16* __restrict__ full) {
  size_t id4 = (size_t)blockIdx.x * 256 + threadIdx.x;  // 2,097,152 total
  size_t base = id4 * 4;
  int t = (int)(base >> 12);          // B*H = 4096
  int rem = (int)(base & 4095);
  const float* src = (t < MEML) ? (mem + ((size_t)t << 12) + rem)
                                : (x + ((size_t)(t - MEML) << 12) + rem);
  float4 v = *(const float4*)src;
  ushort4 o;
  o.x = f2b(v.x); o.y = f2b(v.y); o.z = f2b(v.z); o.w = f2b(v.w);
  *(ushort4*)(full + base) = o;
}

__global__ __launch_bounds__(256) void k_cvt(const float* __restrict__ src,
                                             u16* __restrict__ dst, int n4) {
  int id = blockIdx.x * 256 + threadIdx.x;
  if (id >= n4) return;
  size_t base = (size_t)id * 4;
  float4 v = *(const float4*)(src + base);
  ushort4 o;
  o.x = f2b(v.x); o.y = f2b(v.y); o.z = f2b(v.z); o.w = f2b(v.w);
  *(ushort4*)(dst + base) = o;
}

// ------------------------- generic bf16 GEMM core -------------------------

template <int BM, int BN, int MF, int NF>
DEV void gemm_core(const u16* __restrict__ A, int lda, const u16* __restrict__ Bt,
                   int ldb, int K, f32x4 (&acc)[MF][NF]) {
  constexpr int WM = 16 * MF, WN = 16 * NF;
  constexpr int WAVES_M = BM / WM, WAVES_N = BN / WN;
  constexpr int THREADS = WAVES_M * WAVES_N * 64;
  constexpr int ITA = (BM * 4) / THREADS;
  constexpr int ITB = (BN * 4) / THREADS;
  __shared__ u16 As[BM * 40];
  __shared__ u16 Bs[BN * 40];
  const int tid = threadIdx.x, lane = tid & 63, wave = tid >> 6;
  const int wm = wave / WAVES_N, wn = wave % WAVES_N;
#pragma unroll
  for (int fm = 0; fm < MF; ++fm)
#pragma unroll
    for (int fn = 0; fn < NF; ++fn) acc[fm][fn] = fzero();

  for (int k0 = 0; k0 < K; k0 += 32) {
    __syncthreads();
#pragma unroll
    for (int it = 0; it < ITA; ++it) {
      int c = tid + it * THREADS;
      int r = c >> 2, kc = c & 3;
      *(uint4*)(As + r * 40 + kc * 8) =
          *(const uint4*)(A + (size_t)r * lda + k0 + kc * 8);
    }
#pragma unroll
    for (int it = 0; it < ITB; ++it) {
      int c = tid + it * THREADS;
      int r = c >> 2, kc = c & 3;
      *(uint4*)(Bs + r * 40 + kc * 8) =
          *(const uint4*)(Bt + (size_t)r * ldb + k0 + kc * 8);
    }
    __syncthreads();
    bf16x8 af[MF], bfr[NF];
#pragma unroll
    for (int fm = 0; fm < MF; ++fm)
      af[fm] = *(const bf16x8*)(As + (wm * WM + fm * 16 + (lane & 15)) * 40 +
                                ((lane >> 4) << 3));
#pragma unroll
    for (int fn = 0; fn < NF; ++fn)
      bfr[fn] = *(const bf16x8*)(Bs + (wn * WN + fn * 16 + (lane & 15)) * 40 +
                                 ((lane >> 4) << 3));
#pragma unroll
    for (int fm = 0; fm < MF; ++fm)
#pragma unroll
      for (int fn = 0; fn < NF; ++fn)
        acc[fm][fn] = mfma16(af[fm], bfr[fn], acc[fm][fn]);
  }
}

template <int BM, int BN, int MF, int NF, class F>
DEV void epi_apply(f32x4 (&acc)[MF][NF], F&& f) {
  constexpr int WAVES_N = BN / (16 * NF);
  const int lane = threadIdx.x & 63, wave = threadIdx.x >> 6;
  const int wm = wave / WAVES_N, wn = wave % WAVES_N;
#pragma unroll
  for (int fm = 0; fm < MF; ++fm)
#pragma unroll
    for (int fn = 0; fn < NF; ++fn)
#pragma unroll
      for (int q = 0; q < 4; ++q) {
        int rl = wm * (16 * MF) + fm * 16 + ((lane >> 4) << 2) + q;
        int cl = wn * (16 * NF) + fn * 16 + (lane & 15);
        f(rl, cl, acc[fm][fn][q]);
      }
}

// ------------------------- GEMM wrappers -------------------------

__global__ __launch_bounds__(256) void k_gemm_qkv(
    const u16* __restrict__ full, const u16* __restrict__ wqkv,
    const float* __restrict__ rwb, const float* __restrict__ rrb,
    u16* __restrict__ qw, u16* __restrict__ qr, u16* __restrict__ kk,
    u16* __restrict__ vt) {
  f32x4 acc[4][4];
  const u16* A = full + (size_t)blockIdx.x * 128 * 1024;
  const u16* Bt = wqkv + (size_t)blockIdx.y * 128 * 1024;
  gemm_core<128, 128, 4, 4>(A, 1024, Bt, 1024, 1024, acc);
  const int row0 = blockIdx.x * 128, col0 = blockIdx.y * 128;
  epi_apply<128, 128, 4, 4>(acc, [&](int rl, int cl, float v) {
    int grow = row0 + rl, gcol = col0 + cl;
    int t = grow >> 2, bb = grow & 3;
    int which = gcol >> 10, hd = gcol & 1023;
    int n = hd >> 6, d = hd & 63;
    if (which == 0) {
      if (t >= MEML) {
        int i = t - MEML;
        size_t o = ((size_t)(bb * NHH + n) * SEQ + i) * HDD + d;
        qw[o] = f2b(v + rwb[hd]);
        qr[o] = f2b(v + rrb[hd]);
      }
    } else if (which == 1) {
      kk[((size_t)(bb * NHH + n) * TOT + t) * HDD + d] = f2b(v);
    } else {
      vt[((size_t)(bb * NHH + n) * HDD + d) * TOT + t] = f2b(v);
    }
  });
}

__global__ __launch_bounds__(256) void k_gemm_rk(const u16* __restrict__ pos,
                                                 const u16* __restrict__ wr,
                                                 u16* __restrict__ rk) {
  f32x4 acc[4][4];
  const u16* A = pos + (size_t)blockIdx.x * 128 * 1024;
  const u16* Bt = wr + (size_t)blockIdx.y * 128 * 1024;
  gemm_core<128, 128, 4, 4>(A, 1024, Bt, 1024, 1024, acc);
  const int row0 = blockIdx.x * 128, col0 = blockIdx.y * 128;
  epi_apply<128, 128, 4, 4>(acc, [&](int rl, int cl, float v) {
    int r = row0 + rl, o = col0 + cl;
    int n = o >> 6, d = o & 63;
    rk[((size_t)n * TOT + r) * HDD + d] = f2b(v);
  });
}

__global__ __launch_bounds__(256) void k_gemm_out(const u16* __restrict__ avec,
                                                  const u16* __restrict__ wo,
                                                  const float* __restrict__ x,
                                                  float* __restrict__ y) {
  f32x4 acc[4][4];
  const u16* A = avec + (size_t)blockIdx.x * 128 * 1024;
  const u16* Bt = wo + (size_t)blockIdx.y * 128 * 1024;
  gemm_core<128, 128, 4, 4>(A, 1024, Bt, 1024, 1024, acc);
  const int row0 = blockIdx.x * 128, col0 = blockIdx.y * 128;
  epi_apply<128, 128, 4, 4>(acc, [&](int rl, int cl, float v) {
    size_t o = (size_t)(row0 + rl) * HH + (col0 + cl);
    y[o] = v + x[o];
  });
}

// ------------------------- fused flash attention (barrier-free) -------------
// Block = (i-tile 64 rows, head n, batch b) via XCD-swizzled 1D grid.
// 4 waves; wave w owns rows w*16..w*16+15 independently. K/R/V fragments are
// read DIRECTLY from global (L1/L2-served; per-(b,n) working set 768KB).
// BDp and Ps are wave-private LDS -> zero __syncthreads in the whole kernel.
// S[i,j] = (qw_i.k_j + qr_i.rk[j-i+1023]) * 0.125; softmax uses exp2 with
// pre-scaled constant (0.125*log2e).

__global__ __launch_bounds__(256, 4) void k_flash(
    const u16* __restrict__ qw, const u16* __restrict__ qr,
    const u16* __restrict__ kk, const u16* __restrict__ rk,
    const u16* __restrict__ vt, u16* __restrict__ avec) {
  __shared__ u16 BDp[64][132];   // bf16 ring: 2x64 cols + 4 pad, rows=i local
  __shared__ u16 Ps[4][16 * 72]; // per-wave P tile 16x64 (72-pitch)
  const int tid = threadIdx.x, lane = tid & 63, w = tid >> 6;
  const int l15 = lane & 15, g = lane >> 4;
  // XCD-aware swizzle: 1024 blocks = 8 XCDs x 128; i-tile fastest within XCD
  const int bid = blockIdx.x;
  const int work = (bid & 7) * 128 + (bid >> 3);
  const int ti = work & 15, pair = work >> 4;
  const int n = pair & 15, b = pair >> 4;
  const int i0 = ti * 64;
  const int bn = b * NHH + n;
  const u16* qwb = qw + ((size_t)bn * SEQ + i0) * HDD;
  const u16* qrb = qr + ((size_t)bn * SEQ + i0) * HDD;
  const u16* kb = kk + (size_t)bn * TOT * HDD;
  const u16* rkb = rk + (size_t)n * TOT * HDD;
  const u16* vtb = vt + (size_t)bn * HDD * TOT;

  // per-wave Q fragments (rows w*16 .. w*16+15) in regs
  bf16x8 qwf[2], qrf[2];
#pragma unroll
  for (int ks = 0; ks < 2; ++ks) {
    int off = (w * 16 + l15) * HDD + ks * 32 + (g << 3);
    qwf[ks] = *(const bf16x8*)(qwb + off);
    qrf[ks] = *(const bf16x8*)(qrb + off);
  }

  const float NEGINF = -__builtin_inff();
  const float C2 = 0.125f * 1.44269504089f;  // scale * log2(e)
  f32x4 oacc[4];
#pragma unroll
  for (int db = 0; db < 4; ++db) oacc[db] = fzero();
  float mrow[4] = {NEGINF, NEGINF, NEGINF, NEGINF};
  float lrow[4] = {0.f, 0.f, 0.f, 0.f};

  const int m0 = (960 - i0) / 64;  // first r-tile index (>= 0)

  // BD for r-tile rt via MFMA straight from global rk; write into ring slot.
  auto bdcomp = [&](int rt) {
    f32x4 bd[4];
#pragma unroll
    for (int fn = 0; fn < 4; ++fn) bd[fn] = fzero();
#pragma unroll
    for (int ks = 0; ks < 2; ++ks)
#pragma unroll
      for (int fn = 0; fn < 4; ++fn) {
        int rr = rt * 64 + fn * 16 + l15;
        if (rr > 2047) rr = 2047;  // clamp: garbage only feeds masked elems
        bf16x8 rf = *(const bf16x8*)(rkb + (size_t)rr * HDD + ks * 32 + (g << 3));
        bd[fn] = mfma16(qrf[ks], rf, bd[fn]);
      }
    int slot = (rt & 1) << 6;
#pragma unroll
    for (int fn = 0; fn < 4; ++fn)
#pragma unroll
      for (int q = 0; q < 4; ++q)
        BDp[w * 16 + (g << 2) + q][slot + fn * 16 + l15] = f2b(bd[fn][q]);
  };

  bdcomp(m0);

  const int jtc = i0 / 64 + 17;
  for (int jt = 0; jt < jtc; ++jt) {
    const int rt = m0 + jt + 1;
    const int j0 = jt * 64;
    bdcomp(rt);

    // content scores AC: K fragments straight from global
    f32x4 ac[4];
#pragma unroll
    for (int fn = 0; fn < 4; ++fn) ac[fn] = fzero();
#pragma unroll
    for (int ks = 0; ks < 2; ++ks)
#pragma unroll
      for (int fn = 0; fn < 4; ++fn) {
        bf16x8 kf = *(const bf16x8*)(kb + (size_t)(j0 + fn * 16 + l15) * HDD +
                                     ks * 32 + (g << 3));
        ac[fn] = mfma16(qwf[ks], kf, ac[fn]);
      }

    // assemble S' = (AC + BD) * (scale*log2e), track new row max
    const int d0 = j0 - i0 + 1023;
    float mnew[4];
#pragma unroll
    for (int q = 0; q < 4; ++q) mnew[q] = mrow[q];
#pragma unroll
    for (int fn = 0; fn < 4; ++fn)
#pragma unroll
      for (int q = 0; q < 4; ++q) {
        int di = w * 16 + (g << 2) + q;
        int dj = fn * 16 + l15;
        int r = d0 + dj - di;
        float sv = (ac[fn][q] + b2f(BDp[di][r & 127])) * C2;
        if (j0 + dj > i0 + di + MEML) sv = NEGINF;
        ac[fn][q] = sv;
        mnew[q] = fmaxf(mnew[q], sv);
      }
    // reduce max across the 16-lane column group (rows preserved)
#pragma unroll
    for (int q = 0; q < 4; ++q) {
#pragma unroll
      for (int off = 1; off < 16; off <<= 1)
        mnew[q] = fmaxf(mnew[q], __shfl_xor(mnew[q], off, 64));
    }
    float scale[4];
#pragma unroll
    for (int q = 0; q < 4; ++q) {
      scale[q] = exp2fast(mrow[q] - mnew[q]);  // exp2(-inf) = 0
      mrow[q] = mnew[q];
      lrow[q] *= scale[q];
    }
    // P = exp2(S' - m'); partial row sums stay per-lane (reduced at end)
#pragma unroll
    for (int fn = 0; fn < 4; ++fn)
#pragma unroll
      for (int q = 0; q < 4; ++q) {
        float p = exp2fast(ac[fn][q] - mrow[q]);
        lrow[q] += p;
        Ps[w][((g << 2) + q) * 72 + fn * 16 + l15] = f2b(p);
      }
    // rescale O
#pragma unroll
    for (int db = 0; db < 4; ++db)
#pragma unroll
      for (int q = 0; q < 4; ++q) oacc[db][q] *= scale[q];
    // PV: A = wave-local P from LDS, B = V frags straight from vt[d][t]
#pragma unroll
    for (int ks = 0; ks < 2; ++ks) {
      bf16x8 pa = *(const bf16x8*)(Ps[w] + l15 * 72 + ks * 32 + (g << 3));
#pragma unroll
      for (int db = 0; db < 4; ++db) {
        bf16x8 vf = *(const bf16x8*)(vtb + (size_t)(db * 16 + l15) * TOT + j0 +
                                     ks * 32 + (g << 3));
        oacc[db] = mfma16(pa, vf, oacc[db]);
      }
    }
  }

  // final: full row sums, normalize, write avec
#pragma unroll
  for (int q = 0; q < 4; ++q) {
#pragma unroll
    for (int off = 1; off < 16; off <<= 1) lrow[q] += __shfl_xor(lrow[q], off, 64);
    lrow[q] = 1.f / lrow[q];
  }
#pragma unroll
  for (int db = 0; db < 4; ++db)
#pragma unroll
    for (int q = 0; q < 4; ++q) {
      int i = i0 + w * 16 + (g << 2) + q;
      avec[((size_t)i * BB + b) * HH + n * HDD + db * 16 + l15] =
          f2b(oacc[db][q] * lrow[q]);
    }
}

// ------------------------- residual + LayerNorm -------------------------

__global__ __launch_bounds__(256) void k_ln(const float* __restrict__ y,
                                            const float* __restrict__ lw,
                                            const float* __restrict__ lb,
                                            float* __restrict__ out) {
  const int row = blockIdx.x, tid = threadIdx.x;
  const float4 v = *(const float4*)(y + (size_t)row * HH + tid * 4);
  float s = v.x + v.y + v.z + v.w;
  float ss = v.x * v.x + v.y * v.y + v.z * v.z + v.w * v.w;
#pragma unroll
  for (int off = 1; off < 64; off <<= 1) {
    s += __shfl_xor(s, off, 64);
    ss += __shfl_xor(ss, off, 64);
  }
  __shared__ float red[8];
  const int w = tid >> 6, lane = tid & 63;
  if (lane == 0) { red[w] = s; red[4 + w] = ss; }
  __syncthreads();
  float tot = red[0] + red[1] + red[2] + red[3];
  float tss = red[4] + red[5] + red[6] + red[7];
  float mu = tot * (1.f / 1024.f);
  float var = tss * (1.f / 1024.f) - mu * mu;
  float rs = rsqrtf(var + 1e-5f);
  float4 wv = *(const float4*)(lw + tid * 4);
  float4 bv = *(const float4*)(lb + tid * 4);
  float4 o;
  o.x = (v.x - mu) * rs * wv.x + bv.x;
  o.y = (v.y - mu) * rs * wv.y + bv.y;
  o.z = (v.z - mu) * rs * wv.z + bv.z;
  o.w = (v.w - mu) * rs * wv.w + bv.w;
  *(float4*)(out + (size_t)row * HH + tid * 4) = o;
}

// ------------------------- launch -------------------------

extern "C" void kernel_launch(void* const* d_in, const int* in_sizes, int n_in,
                              void* d_out, int out_size, void* d_ws,
                              size_t ws_size, hipStream_t stream) {
  const float* x = (const float*)d_in[0];
  const float* pos = (const float*)d_in[1];
  const float* rwb = (const float*)d_in[2];
  const float* rrb = (const float*)d_in[3];
  // d_in[4] = attn_mask, recomputed analytically
  const float* mem = (const float*)d_in[5];
  const float* wqkv = (const float*)d_in[6];
  const float* wr = (const float*)d_in[7];
  const float* wo = (const float*)d_in[8];
  const float* lnw = (const float*)d_in[9];
  const float* lnb = (const float*)d_in[10];

  char* ws = (char*)d_ws;
  const size_t O_FULL = 0;              // 16,777,216 B (aliased by y later)
  const size_t O_WQKV = 16777216;       // 6,291,456
  const size_t O_WR = 23068672;         // 2,097,152
  const size_t O_WO = 25165824;         // 2,097,152
  const size_t O_POS = 27262976;        // 4,194,304
  const size_t O_QW = 31457280;         // 8,388,608
  const size_t O_QR = 39845888;         // 8,388,608
  const size_t O_K = 48234496;          // 16,777,216
  const size_t O_VT = 65011712;         // 16,777,216
  const size_t O_RK = 81788928;         // 4,194,304
  const size_t O_AVEC = 85983232;       // 8,388,608
  const size_t NEED = 94371840;

  if (ws_size < NEED) return;  // fail visibly

  u16* full = (u16*)(ws + O_FULL);
  u16* wqkv_b = (u16*)(ws + O_WQKV);
  u16* wr_b = (u16*)(ws + O_WR);
  u16* wo_b = (u16*)(ws + O_WO);
  u16* pos_b = (u16*)(ws + O_POS);
  u16* qw = (u16*)(ws + O_QW);
  u16* qr = (u16*)(ws + O_QR);
  u16* kk = (u16*)(ws + O_K);
  u16* vt = (u16*)(ws + O_VT);
  u16* rk = (u16*)(ws + O_RK);
  u16* avec = (u16*)(ws + O_AVEC);
  float* y = (float*)(ws + O_FULL);  // alias: full dead after QKV GEMM

  k_pack<<<8192, 256, 0, stream>>>(mem, x, full);
  k_cvt<<<3072, 256, 0, stream>>>(wqkv, wqkv_b, 786432);
  k_cvt<<<1024, 256, 0, stream>>>(wr, wr_b, 262144);
  k_cvt<<<1024, 256, 0, stream>>>(wo, wo_b, 262144);
  k_cvt<<<2048, 256, 0, stream>>>(pos, pos_b, 524288);

  k_gemm_qkv<<<dim3(64, 24), 256, 0, stream>>>(full, wqkv_b, rwb, rrb, qw, qr,
                                               kk, vt);
  k_gemm_rk<<<dim3(16, 8), 256, 0, stream>>>(pos_b, wr_b, rk);

  k_flash<<<dim3(1024), 256, 0, stream>>>(qw, qr, kk, rk, vt, avec);

  k_gemm_out<<<dim3(32, 8), 256, 0, stream>>>(avec, wo_b, x, y);
  k_ln<<<4096, 256, 0, stream>>>(y, lnw, lnb, (float*)d_out);
}

// Round 5
// 395.093 us; speedup vs baseline: 1.3220x; 1.3220x over previous
//
#include <hip/hip_runtime.h>
#include <stdint.h>

typedef unsigned short u16;
typedef __bf16 bf16t;
typedef bf16t bf16x8 __attribute__((ext_vector_type(8)));
typedef float f32x4 __attribute__((ext_vector_type(4)));

#define DEV static __device__ __forceinline__

DEV u16 f2b(float f) {
  unsigned u = __float_as_uint(f);
  return (u16)((u + 0x7fffu + ((u >> 16) & 1u)) >> 16);
}
DEV float b2f(u16 h) { return __uint_as_float(((unsigned)h) << 16); }
DEV f32x4 fzero() { f32x4 v = {0.f, 0.f, 0.f, 0.f}; return v; }
DEV f32x4 mfma16(bf16x8 a, bf16x8 b, f32x4 c) {
  return __builtin_amdgcn_mfma_f32_16x16x32_bf16(a, b, c, 0, 0, 0);
}
DEV float exp2fast(float x) { return __builtin_amdgcn_exp2f(x); }  // v_exp_f32

// Problem constants
#define SEQ 1024
#define MEML 1024
#define BB 4
#define HH 1024
#define NHH 16
#define HDD 64
#define TOT 2048

// ------------------------- elementwise converts -------------------------

__global__ __launch_bounds__(256) void k_pack(const float* __restrict__ mem,
                                              const float* __restrict__ x,
                                              u16* __restrict__ full) {
  size_t id4 = (size_t)blockIdx.x * 256 + threadIdx.x;  // 2,097,152 total
  size_t base = id4 * 4;
  int t = (int)(base >> 12);          // B*H = 4096
  int rem = (int)(base & 4095);
  const float* src = (t < MEML) ? (mem + ((size_t)t << 12) + rem)
                                : (x + ((size_t)(t - MEML) << 12) + rem);
  float4 v = *(const float4*)src;
  ushort4 o;
  o.x = f2b(v.x); o.y = f2b(v.y); o.z = f2b(v.z); o.w = f2b(v.w);
  *(ushort4*)(full + base) = o;
}

__global__ __launch_bounds__(256) void k_cvt(const float* __restrict__ src,
                                             u16* __restrict__ dst, int n4) {
  int id = blockIdx.x * 256 + threadIdx.x;
  if (id >= n4) return;
  size_t base = (size_t)id * 4;
  float4 v = *(const float4*)(src + base);
  ushort4 o;
  o.x = f2b(v.x); o.y = f2b(v.y); o.z = f2b(v.z); o.w = f2b(v.w);
  *(ushort4*)(dst + base) = o;
}

// ------------------------- generic bf16 GEMM core -------------------------

template <int BM, int BN, int MF, int NF>
DEV void gemm_core(const u16* __restrict__ A, int lda, const u16* __restrict__ Bt,
                   int ldb, int K, f32x4 (&acc)[MF][NF]) {
  constexpr int WM = 16 * MF, WN = 16 * NF;
  constexpr int WAVES_M = BM / WM, WAVES_N = BN / WN;
  constexpr int THREADS = WAVES_M * WAVES_N * 64;
  constexpr int ITA = (BM * 4) / THREADS;
  constexpr int ITB = (BN * 4) / THREADS;
  __shared__ u16 As[BM * 40];
  __shared__ u16 Bs[BN * 40];
  const int tid = threadIdx.x, lane = tid & 63, wave = tid >> 6;
  const int wm = wave / WAVES_N, wn = wave % WAVES_N;
#pragma unroll
  for (int fm = 0; fm < MF; ++fm)
#pragma unroll
    for (int fn = 0; fn < NF; ++fn) acc[fm][fn] = fzero();

  for (int k0 = 0; k0 < K; k0 += 32) {
    __syncthreads();
#pragma unroll
    for (int it = 0; it < ITA; ++it) {
      int c = tid + it * THREADS;
      int r = c >> 2, kc = c & 3;
      *(uint4*)(As + r * 40 + kc * 8) =
          *(const uint4*)(A + (size_t)r * lda + k0 + kc * 8);
    }
#pragma unroll
    for (int it = 0; it < ITB; ++it) {
      int c = tid + it * THREADS;
      int r = c >> 2, kc = c & 3;
      *(uint4*)(Bs + r * 40 + kc * 8) =
          *(const uint4*)(Bt + (size_t)r * ldb + k0 + kc * 8);
    }
    __syncthreads();
    bf16x8 af[MF], bfr[NF];
#pragma unroll
    for (int fm = 0; fm < MF; ++fm)
      af[fm] = *(const bf16x8*)(As + (wm * WM + fm * 16 + (lane & 15)) * 40 +
                                ((lane >> 4) << 3));
#pragma unroll
    for (int fn = 0; fn < NF; ++fn)
      bfr[fn] = *(const bf16x8*)(Bs + (wn * WN + fn * 16 + (lane & 15)) * 40 +
                                 ((lane >> 4) << 3));
#pragma unroll
    for (int fm = 0; fm < MF; ++fm)
#pragma unroll
      for (int fn = 0; fn < NF; ++fn)
        acc[fm][fn] = mfma16(af[fm], bfr[fn], acc[fm][fn]);
  }
}

template <int BM, int BN, int MF, int NF, class F>
DEV void epi_apply(f32x4 (&acc)[MF][NF], F&& f) {
  constexpr int WAVES_N = BN / (16 * NF);
  const int lane = threadIdx.x & 63, wave = threadIdx.x >> 6;
  const int wm = wave / WAVES_N, wn = wave % WAVES_N;
#pragma unroll
  for (int fm = 0; fm < MF; ++fm)
#pragma unroll
    for (int fn = 0; fn < NF; ++fn)
#pragma unroll
      for (int q = 0; q < 4; ++q) {
        int rl = wm * (16 * MF) + fm * 16 + ((lane >> 4) << 2) + q;
        int cl = wn * (16 * NF) + fn * 16 + (lane & 15);
        f(rl, cl, acc[fm][fn][q]);
      }
}

// ------------------------- GEMM wrappers -------------------------

__global__ __launch_bounds__(256) void k_gemm_qkv(
    const u16* __restrict__ full, const u16* __restrict__ wqkv,
    const float* __restrict__ rwb, const float* __restrict__ rrb,
    u16* __restrict__ qw, u16* __restrict__ qr, u16* __restrict__ kk,
    u16* __restrict__ vt) {
  f32x4 acc[4][4];
  const u16* A = full + (size_t)blockIdx.x * 128 * 1024;
  const u16* Bt = wqkv + (size_t)blockIdx.y * 128 * 1024;
  gemm_core<128, 128, 4, 4>(A, 1024, Bt, 1024, 1024, acc);
  const int row0 = blockIdx.x * 128, col0 = blockIdx.y * 128;
  epi_apply<128, 128, 4, 4>(acc, [&](int rl, int cl, float v) {
    int grow = row0 + rl, gcol = col0 + cl;
    int t = grow >> 2, bb = grow & 3;
    int which = gcol >> 10, hd = gcol & 1023;
    int n = hd >> 6, d = hd & 63;
    if (which == 0) {
      if (t >= MEML) {
        int i = t - MEML;
        size_t o = ((size_t)(bb * NHH + n) * SEQ + i) * HDD + d;
        qw[o] = f2b(v + rwb[hd]);
        qr[o] = f2b(v + rrb[hd]);
      }
    } else if (which == 1) {
      kk[((size_t)(bb * NHH + n) * TOT + t) * HDD + d] = f2b(v);
    } else {
      vt[((size_t)(bb * NHH + n) * HDD + d) * TOT + t] = f2b(v);
    }
  });
}

__global__ __launch_bounds__(256) void k_gemm_rk(const u16* __restrict__ pos,
                                                 const u16* __restrict__ wr,
                                                 u16* __restrict__ rk) {
  f32x4 acc[4][4];
  const u16* A = pos + (size_t)blockIdx.x * 128 * 1024;
  const u16* Bt = wr + (size_t)blockIdx.y * 128 * 1024;
  gemm_core<128, 128, 4, 4>(A, 1024, Bt, 1024, 1024, acc);
  const int row0 = blockIdx.x * 128, col0 = blockIdx.y * 128;
  epi_apply<128, 128, 4, 4>(acc, [&](int rl, int cl, float v) {
    int r = row0 + rl, o = col0 + cl;
    int n = o >> 6, d = o & 63;
    rk[((size_t)n * TOT + r) * HDD + d] = f2b(v);
  });
}

__global__ __launch_bounds__(256) void k_gemm_out(const u16* __restrict__ avec,
                                                  const u16* __restrict__ wo,
                                                  const float* __restrict__ x,
                                                  float* __restrict__ y) {
  f32x4 acc[4][4];
  const u16* A = avec + (size_t)blockIdx.x * 128 * 1024;
  const u16* Bt = wo + (size_t)blockIdx.y * 128 * 1024;
  gemm_core<128, 128, 4, 4>(A, 1024, Bt, 1024, 1024, acc);
  const int row0 = blockIdx.x * 128, col0 = blockIdx.y * 128;
  epi_apply<128, 128, 4, 4>(acc, [&](int rl, int cl, float v) {
    size_t o = (size_t)(row0 + rl) * HH + (col0 + cl);
    y[o] = v + x[o];
  });
}

// ------------------------- fused flash attention (pipelined LDS) -----------
// Block = (64-row i-tile, head n, batch b), XCD-swizzled grid, 4 waves.
// Per iteration (one 64-col j-tile): ONE barrier.
//   top:  issue coalesced K/V[t+1] global->reg loads; issue R-fragment loads
//         for BD tile t+2 (gather, latency hidden under compute)
//   mid:  AC mfma from swizzled LDS K; S = (AC+BD)*C2 (BDp ready from t-1);
//         online softmax (defer-max THR=8); P->Ps (swizzled); PV from LDS V
//   tail: bd_comp(t+2) -> BDp ring (off critical path); ds_write staged K/V;
//         __syncthreads()
// XOR swizzle (T2): u16 off ^ ((row&7)<<3) kills 128B-row bank conflicts.

__global__ __launch_bounds__(256, 2) void k_flash(
    const u16* __restrict__ qw, const u16* __restrict__ qr,
    const u16* __restrict__ kk, const u16* __restrict__ rk,
    const u16* __restrict__ vt, u16* __restrict__ avec) {
  __shared__ __align__(16) u16 Kb[2 * 4096];       // [slot][row j 0..63][64]
  __shared__ __align__(16) u16 Vb[2 * 4096];       // [slot][row d 0..63][64]
  __shared__ __align__(16) u16 BDp[2 * 64 * 68];   // [slot][r&63][di], pitch 68
  __shared__ __align__(16) u16 Ps[4 * 1024];       // per-wave 16x64, swizzled
  const int tid = threadIdx.x, lane = tid & 63, w = tid >> 6;
  const int l15 = lane & 15, g = lane >> 4;
  const int bid = blockIdx.x;
  const int work = (bid & 7) * 128 + (bid >> 3);   // XCD-aware swizzle
  const int ti = work & 15, pair = work >> 4;
  const int n = pair & 15, b = pair >> 4;
  const int i0 = ti * 64;
  const int bn = b * NHH + n;
  const u16* qwb = qw + ((size_t)bn * SEQ + i0) * HDD;
  const u16* qrb = qr + ((size_t)bn * SEQ + i0) * HDD;
  const u16* kb = kk + (size_t)bn * TOT * HDD;
  const u16* rkb = rk + (size_t)n * TOT * HDD;
  const u16* vtb = vt + (size_t)bn * HDD * TOT;

  // per-wave Q fragments (rows w*16 .. w*16+15) in regs
  bf16x8 qwf[2], qrf[2];
#pragma unroll
  for (int ks = 0; ks < 2; ++ks) {
    int off = (w * 16 + l15) * HDD + ks * 32 + (g << 3);
    qwf[ks] = *(const bf16x8*)(qwb + off);
    qrf[ks] = *(const bf16x8*)(qrb + off);
  }

  const float NEGINF = -__builtin_inff();
  const float C2 = 0.125f * 1.44269504089f;  // scale * log2(e)
  f32x4 oacc[4];
#pragma unroll
  for (int db = 0; db < 4; ++db) oacc[db] = fzero();
  float mrow[4] = {NEGINF, NEGINF, NEGINF, NEGINF};
  float lrow[4] = {0.f, 0.f, 0.f, 0.f};

  const int m0 = 15 - ti;      // first r-tile
  const int jtc = ti + 17;     // j-tiles to process

  const int sr = (w << 4) + (lane >> 3);  // staging row (this wave: 16 rows)
  const int sc = (lane & 7) << 3;         // staging col (u16 units)
  const int sx = sc ^ ((sr & 7) << 3);    // swizzled LDS col
  uint4 kg[2], vg[2];
  bf16x8 rfr[8];

  auto stage_issue = [&](int jn) {
    kg[0] = *(const uint4*)(kb + (size_t)((jn << 6) + sr) * HDD + sc);
    kg[1] = *(const uint4*)(kb + (size_t)((jn << 6) + sr + 8) * HDD + sc);
    vg[0] = *(const uint4*)(vtb + (size_t)sr * TOT + (jn << 6) + sc);
    vg[1] = *(const uint4*)(vtb + (size_t)(sr + 8) * TOT + (jn << 6) + sc);
  };
  auto stage_write = [&](int slot) {
    u16* kd = Kb + (slot << 12);
    u16* vd = Vb + (slot << 12);
    *(uint4*)(kd + (sr << 6) + sx) = kg[0];
    *(uint4*)(kd + ((sr + 8) << 6) + sx) = kg[1];
    *(uint4*)(vd + (sr << 6) + sx) = vg[0];
    *(uint4*)(vd + ((sr + 8) << 6) + sx) = vg[1];
  };
  auto bd_issue = [&](int rt) {
#pragma unroll
    for (int fn = 0; fn < 4; ++fn) {
      int row = (rt << 6) + fn * 16 + l15;
      row = row > 2047 ? 2047 : row;  // clamp: garbage only feeds masked elems
#pragma unroll
      for (int ks = 0; ks < 2; ++ks)
        rfr[ks * 4 + fn] =
            *(const bf16x8*)(rkb + (size_t)row * HDD + ks * 32 + (g << 3));
    }
  };
  auto bd_comp = [&](int rt) {
    f32x4 bd[4];
#pragma unroll
    for (int fn = 0; fn < 4; ++fn) bd[fn] = fzero();
#pragma unroll
    for (int ks = 0; ks < 2; ++ks)
#pragma unroll
      for (int fn = 0; fn < 4; ++fn)
        bd[fn] = mfma16(qrf[ks], rfr[ks * 4 + fn], bd[fn]);
    u16* dst = BDp + ((rt & 1) ? 4352 : 0);
#pragma unroll
    for (int fn = 0; fn < 4; ++fn) {
      ushort4 pk = {f2b(bd[fn][0]), f2b(bd[fn][1]), f2b(bd[fn][2]),
                    f2b(bd[fn][3])};
      *(ushort4*)(dst + (fn * 16 + l15) * 68 + (w << 4) + (g << 2)) = pk;
    }
  };

  // prologue: stage tile 0; BD tiles m0, m0+1
  stage_issue(0);
  bd_issue(m0);
  bd_comp(m0);
  bd_issue(m0 + 1);
  bd_comp(m0 + 1);
  stage_write(0);
  __syncthreads();

  for (int jt = 0; jt < jtc; ++jt) {
    const int j0 = jt << 6;
    const int jn = (jt + 1 < jtc) ? jt + 1 : jt;
    stage_issue(jn);
    {
      int rts = m0 + jt + 2;
      if (rts > m0 + jtc) rts = m0 + jtc;
      bd_issue(rts);
    }

    // AC from swizzled LDS K
    const u16* kbuf = Kb + ((jt & 1) << 12);
    f32x4 ac[4];
#pragma unroll
    for (int fn = 0; fn < 4; ++fn) ac[fn] = fzero();
#pragma unroll
    for (int ks = 0; ks < 2; ++ks)
#pragma unroll
      for (int fn = 0; fn < 4; ++fn) {
        int row = fn * 16 + l15;
        bf16x8 kf = *(const bf16x8*)(kbuf + (row << 6) +
                                     ((ks * 32 + (g << 3)) ^ ((row & 7) << 3)));
        ac[fn] = mfma16(qwf[ks], kf, ac[fn]);
      }

    // S = (AC + BD)*C2, mask only on last tile; track per-row max
    const int d0 = j0 - i0 + 1023;
    const bool last = (jt == jtc - 1);
    float pmax[4] = {NEGINF, NEGINF, NEGINF, NEGINF};
#pragma unroll
    for (int fn = 0; fn < 4; ++fn)
#pragma unroll
      for (int q = 0; q < 4; ++q) {
        int di = (w << 4) + (g << 2) + q;
        int dj = fn * 16 + l15;
        int r = d0 + dj - di;
        float sv =
            (ac[fn][q] +
             b2f(BDp[((r >> 6) & 1) * 4352 + (r & 63) * 68 + di])) * C2;
        if (last && dj > di) sv = NEGINF;
        ac[fn][q] = sv;
        pmax[q] = fmaxf(pmax[q], sv);
      }
#pragma unroll
    for (int q = 0; q < 4; ++q) {
#pragma unroll
      for (int off = 1; off < 16; off <<= 1)
        pmax[q] = fmaxf(pmax[q], __shfl_xor(pmax[q], off, 64));
    }
    // defer-max (T13): rescale only if max grew by > 8 (log2 domain)
    int need = (pmax[0] > mrow[0] + 8.f) | (pmax[1] > mrow[1] + 8.f) |
               (pmax[2] > mrow[2] + 8.f) | (pmax[3] > mrow[3] + 8.f);
    if (__any(need)) {
#pragma unroll
      for (int q = 0; q < 4; ++q) {
        float mn = fmaxf(mrow[q], pmax[q]);
        float sc2 = exp2fast(mrow[q] - mn);  // exp2(-inf)=0
        mrow[q] = mn;
        lrow[q] *= sc2;
#pragma unroll
        for (int db = 0; db < 4; ++db) oacc[db][q] *= sc2;
      }
    }
    // P = exp2(S - m) -> Ps (swizzled, wave-private)
    u16* ps = Ps + (w << 10);
#pragma unroll
    for (int fn = 0; fn < 4; ++fn)
#pragma unroll
      for (int q = 0; q < 4; ++q) {
        float p = exp2fast(ac[fn][q] - mrow[q]);
        lrow[q] += p;
        int row = (g << 2) + q, col = fn * 16 + l15;
        ps[(row << 6) + (col ^ ((row & 7) << 3))] = f2b(p);
      }
    // PV from swizzled LDS V
    const u16* vbuf = Vb + ((jt & 1) << 12);
#pragma unroll
    for (int ks = 0; ks < 2; ++ks) {
      bf16x8 pa = *(const bf16x8*)(ps + (l15 << 6) +
                                   ((ks * 32 + (g << 3)) ^ ((l15 & 7) << 3)));
#pragma unroll
      for (int db = 0; db < 4; ++db) {
        int row = db * 16 + l15;
        bf16x8 vf = *(const bf16x8*)(vbuf + (row << 6) +
                                     ((ks * 32 + (g << 3)) ^ ((row & 7) << 3)));
        oacc[db] = mfma16(pa, vf, oacc[db]);
      }
    }
    // tail: BD for tile t+2 (read next iter), staged K/V writes, barrier
    if (jt + 2 <= jtc) bd_comp(m0 + jt + 2);
    stage_write((jt + 1) & 1);
    __syncthreads();
  }

  // final: full row sums, normalize, write avec
#pragma unroll
  for (int q = 0; q < 4; ++q) {
#pragma unroll
    for (int off = 1; off < 16; off <<= 1)
      lrow[q] += __shfl_xor(lrow[q], off, 64);
    lrow[q] = 1.f / lrow[q];
  }
#pragma unroll
  for (int db = 0; db < 4; ++db)
#pragma unroll
    for (int q = 0; q < 4; ++q) {
      int i = i0 + (w << 4) + (g << 2) + q;
      avec[((size_t)i * BB + b) * HH + n * HDD + db * 16 + l15] =
          f2b(oacc[db][q] * lrow[q]);
    }
}

// ------------------------- residual + LayerNorm -------------------------

__global__ __launch_bounds__(256) void k_ln(const float* __restrict__ y,
                                            const float* __restrict__ lw,
                                            const float* __restrict__ lb,
                                            float* __restrict__ out) {
  const int row = blockIdx.x, tid = threadIdx.x;
  const float4 v = *(const float4*)(y + (size_t)row * HH + tid * 4);
  float s = v.x + v.y + v.z + v.w;
  float ss = v.x * v.x + v.y * v.y + v.z * v.z + v.w * v.w;
#pragma unroll
  for (int off = 1; off < 64; off <<= 1) {
    s += __shfl_xor(s, off, 64);
    ss += __shfl_xor(ss, off, 64);
  }
  __shared__ float red[8];
  const int w = tid >> 6, lane = tid & 63;
  if (lane == 0) { red[w] = s; red[4 + w] = ss; }
  __syncthreads();
  float tot = red[0] + red[1] + red[2] + red[3];
  float tss = red[4] + red[5] + red[6] + red[7];
  float mu = tot * (1.f / 1024.f);
  float var = tss * (1.f / 1024.f) - mu * mu;
  float rs = rsqrtf(var + 1e-5f);
  float4 wv = *(const float4*)(lw + tid * 4);
  float4 bv = *(const float4*)(lb + tid * 4);
  float4 o;
  o.x = (v.x - mu) * rs * wv.x + bv.x;
  o.y = (v.y - mu) * rs * wv.y + bv.y;
  o.z = (v.z - mu) * rs * wv.z + bv.z;
  o.w = (v.w - mu) * rs * wv.w + bv.w;
  *(float4*)(out + (size_t)row * HH + tid * 4) = o;
}

// ------------------------- launch -------------------------

extern "C" void kernel_launch(void* const* d_in, const int* in_sizes, int n_in,
                              void* d_out, int out_size, void* d_ws,
                              size_t ws_size, hipStream_t stream) {
  const float* x = (const float*)d_in[0];
  const float* pos = (const float*)d_in[1];
  const float* rwb = (const float*)d_in[2];
  const float* rrb = (const float*)d_in[3];
  // d_in[4] = attn_mask, recomputed analytically
  const float* mem = (const float*)d_in[5];
  const float* wqkv = (const float*)d_in[6];
  const float* wr = (const float*)d_in[7];
  const float* wo = (const float*)d_in[8];
  const float* lnw = (const float*)d_in[9];
  const float* lnb = (const float*)d_in[10];

  char* ws = (char*)d_ws;
  const size_t O_FULL = 0;              // 16,777,216 B (aliased by y later)
  const size_t O_WQKV = 16777216;       // 6,291,456
  const size_t O_WR = 23068672;         // 2,097,152
  const size_t O_WO = 25165824;         // 2,097,152
  const size_t O_POS = 27262976;        // 4,194,304
  const size_t O_QW = 31457280;         // 8,388,608
  const size_t O_QR = 39845888;         // 8,388,608
  const size_t O_K = 48234496;          // 16,777,216
  const size_t O_VT = 65011712;         // 16,777,216
  const size_t O_RK = 81788928;         // 4,194,304
  const size_t O_AVEC = 85983232;       // 8,388,608
  const size_t NEED = 94371840;

  if (ws_size < NEED) return;  // fail visibly

  u16* full = (u16*)(ws + O_FULL);
  u16* wqkv_b = (u16*)(ws + O_WQKV);
  u16* wr_b = (u16*)(ws + O_WR);
  u16* wo_b = (u16*)(ws + O_WO);
  u16* pos_b = (u16*)(ws + O_POS);
  u16* qw = (u16*)(ws + O_QW);
  u16* qr = (u16*)(ws + O_QR);
  u16* kk = (u16*)(ws + O_K);
  u16* vt = (u16*)(ws + O_VT);
  u16* rk = (u16*)(ws + O_RK);
  u16* avec = (u16*)(ws + O_AVEC);
  float* y = (float*)(ws + O_FULL);  // alias: full dead after QKV GEMM

  k_pack<<<8192, 256, 0, stream>>>(mem, x, full);
  k_cvt<<<3072, 256, 0, stream>>>(wqkv, wqkv_b, 786432);
  k_cvt<<<1024, 256, 0, stream>>>(wr, wr_b, 262144);
  k_cvt<<<1024, 256, 0, stream>>>(wo, wo_b, 262144);
  k_cvt<<<2048, 256, 0, stream>>>(pos, pos_b, 524288);

  k_gemm_qkv<<<dim3(64, 24), 256, 0, stream>>>(full, wqkv_b, rwb, rrb, qw, qr,
                                               kk, vt);
  k_gemm_rk<<<dim3(16, 8), 256, 0, stream>>>(pos_b, wr_b, rk);

  k_flash<<<dim3(1024), 256, 0, stream>>>(qw, qr, kk, rk, vt, avec);

  k_gemm_out<<<dim3(32, 8), 256, 0, stream>>>(avec, wo_b, x, y);
  k_ln<<<4096, 256, 0, stream>>>(y, lnw, lnb, (float*)d_out);
}

// Round 6
// 340.613 us; speedup vs baseline: 1.5335x; 1.1599x over previous
//
#include <hip/hip_runtime.h>
#include <stdint.h>

typedef unsigned short u16;
typedef __bf16 bf16t;
typedef bf16t bf16x8 __attribute__((ext_vector_type(8)));
typedef float f32x4 __attribute__((ext_vector_type(4)));

#define DEV static __device__ __forceinline__

DEV u16 f2b(float f) {
  unsigned u = __float_as_uint(f);
  return (u16)((u + 0x7fffu + ((u >> 16) & 1u)) >> 16);
}
DEV u16 bcast(float f) {  // native f32->bf16 (v_cvt, RNE), bit pattern
  union { bf16t b; u16 u; } c;
  c.b = (bf16t)f;
  return c.u;
}
DEV float b2f(u16 h) { return __uint_as_float(((unsigned)h) << 16); }
DEV f32x4 fzero() { f32x4 v = {0.f, 0.f, 0.f, 0.f}; return v; }
DEV f32x4 mfma16(bf16x8 a, bf16x8 b, f32x4 c) {
  return __builtin_amdgcn_mfma_f32_16x16x32_bf16(a, b, c, 0, 0, 0);
}
DEV float exp2fast(float x) { return __builtin_amdgcn_exp2f(x); }  // v_exp_f32

// Problem constants
#define SEQ 1024
#define MEML 1024
#define BB 4
#define HH 1024
#define NHH 16
#define HDD 64
#define TOT 2048

// ------------------------- elementwise converts -------------------------

__global__ __launch_bounds__(256) void k_pack(const float* __restrict__ mem,
                                              const float* __restrict__ x,
                                              u16* __restrict__ full) {
  size_t id4 = (size_t)blockIdx.x * 256 + threadIdx.x;  // 2,097,152 total
  size_t base = id4 * 4;
  int t = (int)(base >> 12);          // B*H = 4096
  int rem = (int)(base & 4095);
  const float* src = (t < MEML) ? (mem + ((size_t)t << 12) + rem)
                                : (x + ((size_t)(t - MEML) << 12) + rem);
  float4 v = *(const float4*)src;
  ushort4 o;
  o.x = f2b(v.x); o.y = f2b(v.y); o.z = f2b(v.z); o.w = f2b(v.w);
  *(ushort4*)(full + base) = o;
}

__global__ __launch_bounds__(256) void k_cvt(const float* __restrict__ src,
                                             u16* __restrict__ dst, int n4) {
  int id = blockIdx.x * 256 + threadIdx.x;
  if (id >= n4) return;
  size_t base = (size_t)id * 4;
  float4 v = *(const float4*)(src + base);
  ushort4 o;
  o.x = f2b(v.x); o.y = f2b(v.y); o.z = f2b(v.z); o.w = f2b(v.w);
  *(ushort4*)(dst + base) = o;
}

// ------------------------- generic bf16 GEMM core -------------------------

template <int BM, int BN, int MF, int NF>
DEV void gemm_core(const u16* __restrict__ A, int lda, const u16* __restrict__ Bt,
                   int ldb, int K, f32x4 (&acc)[MF][NF]) {
  constexpr int WM = 16 * MF, WN = 16 * NF;
  constexpr int WAVES_M = BM / WM, WAVES_N = BN / WN;
  constexpr int THREADS = WAVES_M * WAVES_N * 64;
  constexpr int ITA = (BM * 4) / THREADS;
  constexpr int ITB = (BN * 4) / THREADS;
  __shared__ u16 As[BM * 40];
  __shared__ u16 Bs[BN * 40];
  const int tid = threadIdx.x, lane = tid & 63, wave = tid >> 6;
  const int wm = wave / WAVES_N, wn = wave % WAVES_N;
#pragma unroll
  for (int fm = 0; fm < MF; ++fm)
#pragma unroll
    for (int fn = 0; fn < NF; ++fn) acc[fm][fn] = fzero();

  for (int k0 = 0; k0 < K; k0 += 32) {
    __syncthreads();
#pragma unroll
    for (int it = 0; it < ITA; ++it) {
      int c = tid + it * THREADS;
      int r = c >> 2, kc = c & 3;
      *(uint4*)(As + r * 40 + kc * 8) =
          *(const uint4*)(A + (size_t)r * lda + k0 + kc * 8);
    }
#pragma unroll
    for (int it = 0; it < ITB; ++it) {
      int c = tid + it * THREADS;
      int r = c >> 2, kc = c & 3;
      *(uint4*)(Bs + r * 40 + kc * 8) =
          *(const uint4*)(Bt + (size_t)r * ldb + k0 + kc * 8);
    }
    __syncthreads();
    bf16x8 af[MF], bfr[NF];
#pragma unroll
    for (int fm = 0; fm < MF; ++fm)
      af[fm] = *(const bf16x8*)(As + (wm * WM + fm * 16 + (lane & 15)) * 40 +
                                ((lane >> 4) << 3));
#pragma unroll
    for (int fn = 0; fn < NF; ++fn)
      bfr[fn] = *(const bf16x8*)(Bs + (wn * WN + fn * 16 + (lane & 15)) * 40 +
                                 ((lane >> 4) << 3));
#pragma unroll
    for (int fm = 0; fm < MF; ++fm)
#pragma unroll
      for (int fn = 0; fn < NF; ++fn)
        acc[fm][fn] = mfma16(af[fm], bfr[fn], acc[fm][fn]);
  }
}

template <int BM, int BN, int MF, int NF, class F>
DEV void epi_apply(f32x4 (&acc)[MF][NF], F&& f) {
  constexpr int WAVES_N = BN / (16 * NF);
  const int lane = threadIdx.x & 63, wave = threadIdx.x >> 6;
  const int wm = wave / WAVES_N, wn = wave % WAVES_N;
#pragma unroll
  for (int fm = 0; fm < MF; ++fm)
#pragma unroll
    for (int fn = 0; fn < NF; ++fn)
#pragma unroll
      for (int q = 0; q < 4; ++q) {
        int rl = wm * (16 * MF) + fm * 16 + ((lane >> 4) << 2) + q;
        int cl = wn * (16 * NF) + fn * 16 + (lane & 15);
        f(rl, cl, acc[fm][fn][q]);
      }
}

// ------------------------- GEMM wrappers -------------------------

__global__ __launch_bounds__(256) void k_gemm_qkv(
    const u16* __restrict__ full, const u16* __restrict__ wqkv,
    const float* __restrict__ rwb, const float* __restrict__ rrb,
    u16* __restrict__ qw, u16* __restrict__ qr, u16* __restrict__ kk,
    u16* __restrict__ vt) {
  f32x4 acc[4][4];
  const u16* A = full + (size_t)blockIdx.x * 128 * 1024;
  const u16* Bt = wqkv + (size_t)blockIdx.y * 128 * 1024;
  gemm_core<128, 128, 4, 4>(A, 1024, Bt, 1024, 1024, acc);
  const int row0 = blockIdx.x * 128, col0 = blockIdx.y * 128;
  epi_apply<128, 128, 4, 4>(acc, [&](int rl, int cl, float v) {
    int grow = row0 + rl, gcol = col0 + cl;
    int t = grow >> 2, bb = grow & 3;
    int which = gcol >> 10, hd = gcol & 1023;
    int n = hd >> 6, d = hd & 63;
    if (which == 0) {
      if (t >= MEML) {
        int i = t - MEML;
        size_t o = ((size_t)(bb * NHH + n) * SEQ + i) * HDD + d;
        qw[o] = f2b(v + rwb[hd]);
        qr[o] = f2b(v + rrb[hd]);
      }
    } else if (which == 1) {
      kk[((size_t)(bb * NHH + n) * TOT + t) * HDD + d] = f2b(v);
    } else {
      vt[((size_t)(bb * NHH + n) * HDD + d) * TOT + t] = f2b(v);
    }
  });
}

__global__ __launch_bounds__(256) void k_gemm_rk(const u16* __restrict__ pos,
                                                 const u16* __restrict__ wr,
                                                 u16* __restrict__ rk) {
  f32x4 acc[4][4];
  const u16* A = pos + (size_t)blockIdx.x * 128 * 1024;
  const u16* Bt = wr + (size_t)blockIdx.y * 128 * 1024;
  gemm_core<128, 128, 4, 4>(A, 1024, Bt, 1024, 1024, acc);
  const int row0 = blockIdx.x * 128, col0 = blockIdx.y * 128;
  epi_apply<128, 128, 4, 4>(acc, [&](int rl, int cl, float v) {
    int r = row0 + rl, o = col0 + cl;
    int n = o >> 6, d = o & 63;
    rk[((size_t)n * TOT + r) * HDD + d] = f2b(v);
  });
}

__global__ __launch_bounds__(256) void k_gemm_out(const u16* __restrict__ avec,
                                                  const u16* __restrict__ wo,
                                                  const float* __restrict__ x,
                                                  float* __restrict__ y) {
  f32x4 acc[4][4];
  const u16* A = avec + (size_t)blockIdx.x * 128 * 1024;
  const u16* Bt = wo + (size_t)blockIdx.y * 128 * 1024;
  gemm_core<128, 128, 4, 4>(A, 1024, Bt, 1024, 1024, acc);
  const int row0 = blockIdx.x * 128, col0 = blockIdx.y * 128;
  epi_apply<128, 128, 4, 4>(acc, [&](int rl, int cl, float v) {
    size_t o = (size_t)(row0 + rl) * HH + (col0 + cl);
    y[o] = v + x[o];
  });
}

// ------------------------- fused flash attention (pipelined, hoisted) -------
// Same schedule as v5 (1 barrier/iter, staged K/V, BD ring) but ALL LDS
// addresses are loop-carried VGPRs: d0 advances exactly 64/iter so r&63 is
// iteration-invariant and only the ring-slot parity toggles (cur = sum-cur).
// BD stored pre-scaled by C2 -> S assembly is 1 FMA + 1 shl per element.
// Native bf16 casts; global pointers via incremented offsets; BD work and
// clamping skipped for provably-masked final tiles.

__global__ __launch_bounds__(256, 2) void k_flash(
    const u16* __restrict__ qw, const u16* __restrict__ qr,
    const u16* __restrict__ kk, const u16* __restrict__ rk,
    const u16* __restrict__ vt, u16* __restrict__ avec) {
  __shared__ __align__(16) u16 Kb[2 * 4096];   // [slot][row j][64] swizzled
  __shared__ __align__(16) u16 Vb[2 * 4096];   // [slot][row d][64] swizzled
  __shared__ __align__(16) u16 BDp[64 * 136];  // [rl][slot(68)][di]
  __shared__ __align__(16) u16 Ps[4 * 1024];   // per-wave 16x64 swizzled
  const int tid = threadIdx.x, lane = tid & 63, w = tid >> 6;
  const int l15 = lane & 15, g = lane >> 4;
  const int bid = blockIdx.x;
  const int work = (bid & 7) * 128 + (bid >> 3);  // XCD swizzle
  const int ti = work & 15, pair = work >> 4;
  const int n = pair & 15, b = pair >> 4;
  const int i0 = ti * 64;
  const int bn = b * NHH + n;
  const u16* qwb = qw + ((size_t)bn * SEQ + i0) * HDD;
  const u16* qrb = qr + ((size_t)bn * SEQ + i0) * HDD;
  const u16* kbase = kk + (size_t)bn * TOT * HDD;
  const u16* rbase = rk + (size_t)n * TOT * HDD;
  const u16* vbase = vt + (size_t)bn * HDD * TOT;

  bf16x8 qwf[2], qrf[2];
#pragma unroll
  for (int ks = 0; ks < 2; ++ks) {
    int off = (w * 16 + l15) * HDD + ks * 32 + (g << 3);
    qwf[ks] = *(const bf16x8*)(qwb + off);
    qrf[ks] = *(const bf16x8*)(qrb + off);
  }

  const float NEGINF = -__builtin_inff();
  const float C2 = 0.125f * 1.44269504089f;  // scale * log2(e)
  f32x4 oacc[4];
#pragma unroll
  for (int db = 0; db < 4; ++db) oacc[db] = fzero();
  float mrow[4] = {NEGINF, NEGINF, NEGINF, NEGINF};
  float lrow[4] = {0.f, 0.f, 0.f, 0.f};

  const int m0 = 15 - ti;
  const int jtc = ti + 17;

  const int sr = (w << 4) + (lane >> 3);  // staging row
  const int sc = (lane & 7) << 3;         // staging col (u16)

  // ---- precomputed LDS indices (u16 units) ----
  int bd_rd[16], bd_rs[16];
#pragma unroll
  for (int fn = 0; fn < 4; ++fn)
#pragma unroll
    for (int q = 0; q < 4; ++q) {
      int di = (w << 4) + (g << 2) + q;
      int dj = (fn << 4) + l15;
      int rl = (63 + dj - di) & 63;
      int s0 = ((1023 - i0 + dj - di) >> 6) & 1;
      int a0 = rl * 136 + s0 * 68 + di;
      int a1 = rl * 136 + (s0 ^ 1) * 68 + di;
      bd_rd[fn * 4 + q] = a0;
      bd_rs[fn * 4 + q] = a0 + a1;
    }
  int bd_wr[4], bd_ws[4];
  {
    int colw = (w << 4) + (g << 2);
    int sA = m0 & 1;
#pragma unroll
    for (int fn = 0; fn < 4; ++fn) {
      int wl = (fn << 4) + l15;
      int a0 = wl * 136 + sA * 68 + colw;
      int a1 = wl * 136 + (sA ^ 1) * 68 + colw;
      bd_wr[fn] = a0;
      bd_ws[fn] = a0 + a1;
    }
  }
  int ps_wr[16];
#pragma unroll
  for (int fn = 0; fn < 4; ++fn)
#pragma unroll
    for (int q = 0; q < 4; ++q) {
      int row = (g << 2) + q;
      ps_wr[fn * 4 + q] =
          (w << 10) + (row << 6) + ((((fn << 4) + l15)) ^ ((row & 7) << 3));
    }
  const int psr0 = (w << 10) + (l15 << 6) + ((g << 3) ^ ((l15 & 7) << 3));
  const int psr1 = psr0 ^ 32;
  int kr0 = (l15 << 6) + ((g << 3) ^ ((l15 & 7) << 3));  // slot0, ks0
  int kr1 = kr0 ^ 32;
  int vr0 = kr0, vr1 = kr1;
  const int kwb = (sr << 6) + (sc ^ ((sr & 7) << 3));  // slot0 write base

  // global offsets (u16 units), for tile jn = jt+1 / rt = m0+jt+2
  int koff = (64 + sr) * 64 + sc;
  int voff0 = sr * 2048 + 64 + sc;
  int voff1 = voff0 + 8 * 2048;
  int rvo[4];
#pragma unroll
  for (int fn = 0; fn < 4; ++fn)
    rvo[fn] = (((m0 + 2) << 6) + (fn << 4) + l15) * 64 + (g << 3);

  uint4 kg0, kg1, vg0, vg1;
  bf16x8 rfr[8];

  auto bd_comp_store = [&]() {
    f32x4 bd[4];
#pragma unroll
    for (int fn = 0; fn < 4; ++fn) bd[fn] = fzero();
#pragma unroll
    for (int ks = 0; ks < 2; ++ks)
#pragma unroll
      for (int fn = 0; fn < 4; ++fn)
        bd[fn] = mfma16(qrf[ks], rfr[ks * 4 + fn], bd[fn]);
#pragma unroll
    for (int fn = 0; fn < 4; ++fn) {
      ushort4 pk = {bcast(bd[fn][0] * C2), bcast(bd[fn][1] * C2),
                    bcast(bd[fn][2] * C2), bcast(bd[fn][3] * C2)};
      *(ushort4*)(BDp + bd_wr[fn]) = pk;
      bd_wr[fn] = bd_ws[fn] - bd_wr[fn];
    }
  };

  // ---- prologue: stage j-tile 0 (slot0); BD tiles m0, m0+1 ----
  kg0 = *(const uint4*)(kbase + sr * 64 + sc);
  kg1 = *(const uint4*)(kbase + (sr + 8) * 64 + sc);
  vg0 = *(const uint4*)(vbase + sr * 2048 + sc);
  vg1 = *(const uint4*)(vbase + (sr + 8) * 2048 + sc);
#pragma unroll
  for (int fn = 0; fn < 4; ++fn) {
    int ro = ((m0 << 6) + (fn << 4) + l15) * 64 + (g << 3);
#pragma unroll
    for (int ks = 0; ks < 2; ++ks)
      rfr[ks * 4 + fn] = *(const bf16x8*)(rbase + ro + ks * 32);
  }
  bd_comp_store();
#pragma unroll
  for (int fn = 0; fn < 4; ++fn) {
    int ro = (((m0 + 1) << 6) + (fn << 4) + l15) * 64 + (g << 3);
#pragma unroll
    for (int ks = 0; ks < 2; ++ks)
      rfr[ks * 4 + fn] = *(const bf16x8*)(rbase + ro + ks * 32);
  }
  bd_comp_store();
  *(uint4*)(Kb + kwb) = kg0;
  *(uint4*)(Kb + kwb + 512) = kg1;
  *(uint4*)(Vb + kwb) = vg0;
  *(uint4*)(Vb + kwb + 512) = vg1;
  __syncthreads();
  int kw = kwb ^ 4096;  // loop writes slot (jt+1)&1

  for (int jt = 0; jt < jtc; ++jt) {
    const bool haveStage = (jt + 1 < jtc);
    const bool haveBD = (jt + 3 <= jtc);  // rt = m0+jt+2 <= 31
    if (haveStage) {
      kg0 = *(const uint4*)(kbase + koff);
      kg1 = *(const uint4*)(kbase + koff + 512);
      vg0 = *(const uint4*)(vbase + voff0);
      vg1 = *(const uint4*)(vbase + voff1);
    }
    if (haveBD) {
#pragma unroll
      for (int fn = 0; fn < 4; ++fn)
#pragma unroll
        for (int ks = 0; ks < 2; ++ks)
          rfr[ks * 4 + fn] = *(const bf16x8*)(rbase + rvo[fn] + ks * 32);
    }

    // AC from swizzled LDS K
    f32x4 ac[4];
#pragma unroll
    for (int fn = 0; fn < 4; ++fn) ac[fn] = fzero();
#pragma unroll
    for (int fn = 0; fn < 4; ++fn) {
      bf16x8 kf = *(const bf16x8*)(Kb + kr0 + fn * 1024);
      ac[fn] = mfma16(qwf[0], kf, ac[fn]);
    }
#pragma unroll
    for (int fn = 0; fn < 4; ++fn) {
      bf16x8 kf = *(const bf16x8*)(Kb + kr1 + fn * 1024);
      ac[fn] = mfma16(qwf[1], kf, ac[fn]);
    }

    // S = fma(ac, C2, bd_prescaled); mask only on last tile; row max
    const bool last = (jt == jtc - 1);
    float pmax[4] = {NEGINF, NEGINF, NEGINF, NEGINF};
#pragma unroll
    for (int fn = 0; fn < 4; ++fn)
#pragma unroll
      for (int q = 0; q < 4; ++q) {
        float bdv = b2f(BDp[bd_rd[fn * 4 + q]]);
        float sv = __builtin_fmaf(ac[fn][q], C2, bdv);
        if (last) {
          int di = (g << 2) + q;       // w-part cancels: compare dj vs di
          int dj = (fn << 4) + l15 - (w << 4);
          if (dj > di) sv = NEGINF;
        }
        ac[fn][q] = sv;
        pmax[q] = fmaxf(pmax[q], sv);
      }
#pragma unroll
    for (int q = 0; q < 4; ++q) {
#pragma unroll
      for (int off = 1; off < 16; off <<= 1)
        pmax[q] = fmaxf(pmax[q], __shfl_xor(pmax[q], off, 64));
    }
    // defer-max (T13)
    int need = (pmax[0] > mrow[0] + 8.f) | (pmax[1] > mrow[1] + 8.f) |
               (pmax[2] > mrow[2] + 8.f) | (pmax[3] > mrow[3] + 8.f);
    if (__any(need)) {
#pragma unroll
      for (int q = 0; q < 4; ++q) {
        float mn = fmaxf(mrow[q], pmax[q]);
        float sc2 = exp2fast(mrow[q] - mn);
        mrow[q] = mn;
        lrow[q] *= sc2;
#pragma unroll
        for (int db = 0; db < 4; ++db) oacc[db][q] *= sc2;
      }
    }
    // P = exp2(S - m) -> Ps (precomputed swizzled addrs)
#pragma unroll
    for (int fn = 0; fn < 4; ++fn)
#pragma unroll
      for (int q = 0; q < 4; ++q) {
        float p = exp2fast(ac[fn][q] - mrow[q]);
        lrow[q] += p;
        Ps[ps_wr[fn * 4 + q]] = bcast(p);
      }
    // PV from swizzled LDS V
    {
      bf16x8 pa0 = *(const bf16x8*)(Ps + psr0);
      bf16x8 pa1 = *(const bf16x8*)(Ps + psr1);
#pragma unroll
      for (int db = 0; db < 4; ++db) {
        bf16x8 vf = *(const bf16x8*)(Vb + vr0 + db * 1024);
        oacc[db] = mfma16(pa0, vf, oacc[db]);
      }
#pragma unroll
      for (int db = 0; db < 4; ++db) {
        bf16x8 vf = *(const bf16x8*)(Vb + vr1 + db * 1024);
        oacc[db] = mfma16(pa1, vf, oacc[db]);
      }
    }
    // tail: BD(t+2), staged K/V writes, barrier, toggles
    if (haveBD) bd_comp_store();
    if (haveStage) {
      *(uint4*)(Kb + kw) = kg0;
      *(uint4*)(Kb + kw + 512) = kg1;
      *(uint4*)(Vb + kw) = vg0;
      *(uint4*)(Vb + kw + 512) = vg1;
    }
    __syncthreads();
#pragma unroll
    for (int e = 0; e < 16; ++e) bd_rd[e] = bd_rs[e] - bd_rd[e];
    kr0 ^= 4096; kr1 ^= 4096; vr0 ^= 4096; vr1 ^= 4096; kw ^= 4096;
    koff += 4096; voff0 += 64; voff1 += 64;
#pragma unroll
    for (int fn = 0; fn < 4; ++fn) rvo[fn] += 4096;
  }

  // final: row sums, normalize, write avec
#pragma unroll
  for (int q = 0; q < 4; ++q) {
#pragma unroll
    for (int off = 1; off < 16; off <<= 1)
      lrow[q] += __shfl_xor(lrow[q], off, 64);
    lrow[q] = 1.f / lrow[q];
  }
#pragma unroll
  for (int db = 0; db < 4; ++db)
#pragma unroll
    for (int q = 0; q < 4; ++q) {
      int i = i0 + (w << 4) + (g << 2) + q;
      avec[((size_t)i * BB + b) * HH + n * HDD + db * 16 + l15] =
          bcast(oacc[db][q] * lrow[q]);
    }
}

// ------------------------- residual + LayerNorm -------------------------

__global__ __launch_bounds__(256) void k_ln(const float* __restrict__ y,
                                            const float* __restrict__ lw,
                                            const float* __restrict__ lb,
                                            float* __restrict__ out) {
  const int row = blockIdx.x, tid = threadIdx.x;
  const float4 v = *(const float4*)(y + (size_t)row * HH + tid * 4);
  float s = v.x + v.y + v.z + v.w;
  float ss = v.x * v.x + v.y * v.y + v.z * v.z + v.w * v.w;
#pragma unroll
  for (int off = 1; off < 64; off <<= 1) {
    s += __shfl_xor(s, off, 64);
    ss += __shfl_xor(ss, off, 64);
  }
  __shared__ float red[8];
  const int w = tid >> 6, lane = tid & 63;
  if (lane == 0) { red[w] = s; red[4 + w] = ss; }
  __syncthreads();
  float tot = red[0] + red[1] + red[2] + red[3];
  float tss = red[4] + red[5] + red[6] + red[7];
  float mu = tot * (1.f / 1024.f);
  float var = tss * (1.f / 1024.f) - mu * mu;
  float rs = rsqrtf(var + 1e-5f);
  float4 wv = *(const float4*)(lw + tid * 4);
  float4 bv = *(const float4*)(lb + tid * 4);
  float4 o;
  o.x = (v.x - mu) * rs * wv.x + bv.x;
  o.y = (v.y - mu) * rs * wv.y + bv.y;
  o.z = (v.z - mu) * rs * wv.z + bv.z;
  o.w = (v.w - mu) * rs * wv.w + bv.w;
  *(float4*)(out + (size_t)row * HH + tid * 4) = o;
}

// ------------------------- launch -------------------------

extern "C" void kernel_launch(void* const* d_in, const int* in_sizes, int n_in,
                              void* d_out, int out_size, void* d_ws,
                              size_t ws_size, hipStream_t stream) {
  const float* x = (const float*)d_in[0];
  const float* pos = (const float*)d_in[1];
  const float* rwb = (const float*)d_in[2];
  const float* rrb = (const float*)d_in[3];
  // d_in[4] = attn_mask, recomputed analytically
  const float* mem = (const float*)d_in[5];
  const float* wqkv = (const float*)d_in[6];
  const float* wr = (const float*)d_in[7];
  const float* wo = (const float*)d_in[8];
  const float* lnw = (const float*)d_in[9];
  const float* lnb = (const float*)d_in[10];

  char* ws = (char*)d_ws;
  const size_t O_FULL = 0;              // 16,777,216 B (aliased by y later)
  const size_t O_WQKV = 16777216;       // 6,291,456
  const size_t O_WR = 23068672;         // 2,097,152
  const size_t O_WO = 25165824;         // 2,097,152
  const size_t O_POS = 27262976;        // 4,194,304
  const size_t O_QW = 31457280;         // 8,388,608
  const size_t O_QR = 39845888;         // 8,388,608
  const size_t O_K = 48234496;          // 16,777,216
  const size_t O_VT = 65011712;         // 16,777,216
  const size_t O_RK = 81788928;         // 4,194,304
  const size_t O_AVEC = 85983232;       // 8,388,608
  const size_t NEED = 94371840;

  if (ws_size < NEED) return;  // fail visibly

  u16* full = (u16*)(ws + O_FULL);
  u16* wqkv_b = (u16*)(ws + O_WQKV);
  u16* wr_b = (u16*)(ws + O_WR);
  u16* wo_b = (u16*)(ws + O_WO);
  u16* pos_b = (u16*)(ws + O_POS);
  u16* qw = (u16*)(ws + O_QW);
  u16* qr = (u16*)(ws + O_QR);
  u16* kk = (u16*)(ws + O_K);
  u16* vt = (u16*)(ws + O_VT);
  u16* rk = (u16*)(ws + O_RK);
  u16* avec = (u16*)(ws + O_AVEC);
  float* y = (float*)(ws + O_FULL);  // alias: full dead after QKV GEMM

  k_pack<<<8192, 256, 0, stream>>>(mem, x, full);
  k_cvt<<<3072, 256, 0, stream>>>(wqkv, wqkv_b, 786432);
  k_cvt<<<1024, 256, 0, stream>>>(wr, wr_b, 262144);
  k_cvt<<<1024, 256, 0, stream>>>(wo, wo_b, 262144);
  k_cvt<<<2048, 256, 0, stream>>>(pos, pos_b, 524288);

  k_gemm_qkv<<<dim3(64, 24), 256, 0, stream>>>(full, wqkv_b, rwb, rrb, qw, qr,
                                               kk, vt);
  k_gemm_rk<<<dim3(16, 8), 256, 0, stream>>>(pos_b, wr_b, rk);

  k_flash<<<dim3(1024), 256, 0, stream>>>(qw, qr, kk, rk, vt, avec);

  k_gemm_out<<<dim3(32, 8), 256, 0, stream>>>(avec, wo_b, x, y);
  k_ln<<<4096, 256, 0, stream>>>(y, lnw, lnb, (float*)d_out);
}

// Round 7
// 300.528 us; speedup vs baseline: 1.7380x; 1.1334x over previous
//
#include <hip/hip_runtime.h>
#include <stdint.h>

typedef unsigned short u16;
typedef __bf16 bf16t;
typedef bf16t bf16x8 __attribute__((ext_vector_type(8)));
typedef float f32x4 __attribute__((ext_vector_type(4)));

#define DEV static __device__ __forceinline__

DEV u16 f2b(float f) {
  unsigned u = __float_as_uint(f);
  return (u16)((u + 0x7fffu + ((u >> 16) & 1u)) >> 16);
}
DEV u16 bcast(float f) {  // native f32->bf16 (v_cvt, RNE), bit pattern
  union { bf16t b; u16 u; } c;
  c.b = (bf16t)f;
  return c.u;
}
DEV float b2f(u16 h) { return __uint_as_float(((unsigned)h) << 16); }
DEV f32x4 fzero() { f32x4 v = {0.f, 0.f, 0.f, 0.f}; return v; }
DEV f32x4 mfma16(bf16x8 a, bf16x8 b, f32x4 c) {
  return __builtin_amdgcn_mfma_f32_16x16x32_bf16(a, b, c, 0, 0, 0);
}
DEV float exp2fast(float x) { return __builtin_amdgcn_exp2f(x); }  // v_exp_f32
DEV void gload16(const u16* g, u16* l) {  // async global->LDS, 16B/lane
  __builtin_amdgcn_global_load_lds(
      (const __attribute__((address_space(1))) unsigned int*)g,
      (__attribute__((address_space(3))) unsigned int*)l, 16, 0, 0);
}

// Problem constants
#define SEQ 1024
#define MEML 1024
#define BB 4
#define HH 1024
#define NHH 16
#define HDD 64
#define TOT 2048

// ------------------------- elementwise converts -------------------------

__global__ __launch_bounds__(256) void k_pack(const float* __restrict__ mem,
                                              const float* __restrict__ x,
                                              u16* __restrict__ full) {
  size_t id4 = (size_t)blockIdx.x * 256 + threadIdx.x;  // 2,097,152 total
  size_t base = id4 * 4;
  int t = (int)(base >> 12);          // B*H = 4096
  int rem = (int)(base & 4095);
  const float* src = (t < MEML) ? (mem + ((size_t)t << 12) + rem)
                                : (x + ((size_t)(t - MEML) << 12) + rem);
  float4 v = *(const float4*)src;
  ushort4 o;
  o.x = f2b(v.x); o.y = f2b(v.y); o.z = f2b(v.z); o.w = f2b(v.w);
  *(ushort4*)(full + base) = o;
}

__global__ __launch_bounds__(256) void k_cvt(const float* __restrict__ src,
                                             u16* __restrict__ dst, int n4) {
  int id = blockIdx.x * 256 + threadIdx.x;
  if (id >= n4) return;
  size_t base = (size_t)id * 4;
  float4 v = *(const float4*)(src + base);
  ushort4 o;
  o.x = f2b(v.x); o.y = f2b(v.y); o.z = f2b(v.z); o.w = f2b(v.w);
  *(ushort4*)(dst + base) = o;
}

// -------------- m97-style bf16 GEMM core (global_load_lds) --------------
// 128x128 tile, 256 threads (2x2 waves of 4x4 frags), BK=32, linear LDS,
// async global->LDS staging (16B/lane), 2 barriers per K-step.

template <int MF, int NF>
DEV void gemm_core2(const u16* __restrict__ A, int lda,
                    const u16* __restrict__ Bt, int ldb, int K,
                    f32x4 (&acc)[MF][NF]) {
  __shared__ __align__(16) u16 As[128 * 32];
  __shared__ __align__(16) u16 Bs[128 * 32];
  const int tid = threadIdx.x, lane = tid & 63, wave = tid >> 6;
  const int l15 = lane & 15, g = lane >> 4;
  const int wm = wave >> 1, wn = wave & 1;
#pragma unroll
  for (int fm = 0; fm < MF; ++fm)
#pragma unroll
    for (int fn = 0; fn < NF; ++fn) acc[fm][fn] = fzero();

  // per-thread staging source offsets (row e8>>2, col (e8&3)*8)
  const int e8a = tid, e8b = 256 + tid;
  const int ra0 = e8a >> 2, ca0 = (e8a & 3) << 3;
  const int ra1 = e8b >> 2, ca1 = (e8b & 3) << 3;
  // wave-uniform LDS dest bases (u16 units): call c, wave w -> c*2048 + w*512
  u16* asd0 = As + (wave << 9);
  u16* asd1 = As + 2048 + (wave << 9);
  u16* bsd0 = Bs + (wave << 9);
  u16* bsd1 = Bs + 2048 + (wave << 9);

  for (int k0 = 0; k0 < K; k0 += 32) {
    __syncthreads();  // previous compute done before overwrite
    gload16(A + (size_t)ra0 * lda + k0 + ca0, asd0);
    gload16(A + (size_t)ra1 * lda + k0 + ca1, asd1);
    gload16(Bt + (size_t)ra0 * ldb + k0 + ca0, bsd0);
    gload16(Bt + (size_t)ra1 * ldb + k0 + ca1, bsd1);
    __syncthreads();  // drains vmcnt -> staged data visible
    bf16x8 af[MF], bfr[NF];
#pragma unroll
    for (int fm = 0; fm < MF; ++fm)
      af[fm] = *(const bf16x8*)(As + ((wm * 64 + fm * 16 + l15) << 5) + (g << 3));
#pragma unroll
    for (int fn = 0; fn < NF; ++fn)
      bfr[fn] = *(const bf16x8*)(Bs + ((wn * 64 + fn * 16 + l15) << 5) + (g << 3));
#pragma unroll
    for (int fm = 0; fm < MF; ++fm)
#pragma unroll
      for (int fn = 0; fn < NF; ++fn)
        acc[fm][fn] = mfma16(af[fm], bfr[fn], acc[fm][fn]);
  }
}

template <int BM, int BN, int MF, int NF, class F>
DEV void epi_apply(f32x4 (&acc)[MF][NF], F&& f) {
  constexpr int WAVES_N = BN / (16 * NF);
  const int lane = threadIdx.x & 63, wave = threadIdx.x >> 6;
  const int wm = wave / WAVES_N, wn = wave % WAVES_N;
#pragma unroll
  for (int fm = 0; fm < MF; ++fm)
#pragma unroll
    for (int fn = 0; fn < NF; ++fn)
#pragma unroll
      for (int q = 0; q < 4; ++q) {
        int rl = wm * (16 * MF) + fm * 16 + ((lane >> 4) << 2) + q;
        int cl = wn * (16 * NF) + fn * 16 + (lane & 15);
        f(rl, cl, acc[fm][fn][q]);
      }
}

// ------------------------- GEMM wrappers -------------------------

__global__ __launch_bounds__(256) void k_gemm_qkv(
    const u16* __restrict__ full, const u16* __restrict__ wqkv,
    const float* __restrict__ rwb, const float* __restrict__ rrb,
    u16* __restrict__ qw, u16* __restrict__ qr, u16* __restrict__ kk,
    u16* __restrict__ vt) {
  f32x4 acc[4][4];
  const u16* A = full + (size_t)blockIdx.x * 128 * 1024;
  const u16* Bt = wqkv + (size_t)blockIdx.y * 128 * 1024;
  gemm_core2<4, 4>(A, 1024, Bt, 1024, 1024, acc);
  const int row0 = blockIdx.x * 128, col0 = blockIdx.y * 128;
  epi_apply<128, 128, 4, 4>(acc, [&](int rl, int cl, float v) {
    int grow = row0 + rl, gcol = col0 + cl;
    int t = grow >> 2, bb = grow & 3;
    int which = gcol >> 10, hd = gcol & 1023;
    int n = hd >> 6, d = hd & 63;
    if (which == 0) {
      if (t >= MEML) {
        int i = t - MEML;
        size_t o = ((size_t)(bb * NHH + n) * SEQ + i) * HDD + d;
        qw[o] = f2b(v + rwb[hd]);
        qr[o] = f2b(v + rrb[hd]);
      }
    } else if (which == 1) {
      kk[((size_t)(bb * NHH + n) * TOT + t) * HDD + d] = f2b(v);
    } else {
      vt[((size_t)(bb * NHH + n) * HDD + d) * TOT + t] = f2b(v);
    }
  });
}

__global__ __launch_bounds__(256) void k_gemm_rk(const u16* __restrict__ pos,
                                                 const u16* __restrict__ wr,
                                                 u16* __restrict__ rk) {
  f32x4 acc[4][4];
  const u16* A = pos + (size_t)blockIdx.x * 128 * 1024;
  const u16* Bt = wr + (size_t)blockIdx.y * 128 * 1024;
  gemm_core2<4, 4>(A, 1024, Bt, 1024, 1024, acc);
  const int row0 = blockIdx.x * 128, col0 = blockIdx.y * 128;
  epi_apply<128, 128, 4, 4>(acc, [&](int rl, int cl, float v) {
    int r = row0 + rl, o = col0 + cl;
    int n = o >> 6, d = o & 63;
    rk[((size_t)n * TOT + r) * HDD + d] = f2b(v);
  });
}

__global__ __launch_bounds__(256) void k_gemm_out(const u16* __restrict__ avec,
                                                  const u16* __restrict__ wo,
                                                  const float* __restrict__ x,
                                                  float* __restrict__ y) {
  f32x4 acc[4][4];
  const u16* A = avec + (size_t)blockIdx.x * 128 * 1024;
  const u16* Bt = wo + (size_t)blockIdx.y * 128 * 1024;
  gemm_core2<4, 4>(A, 1024, Bt, 1024, 1024, acc);
  const int row0 = blockIdx.x * 128, col0 = blockIdx.y * 128;
  epi_apply<128, 128, 4, 4>(acc, [&](int rl, int cl, float v) {
    size_t o = (size_t)(row0 + rl) * HH + (col0 + cl);
    y[o] = v + x[o];
  });
}

// ------------------------- fused flash attention (pipelined, hoisted) -------
// v6 structure (1 barrier/iter, staged K/V, BD ring, loop-carried LDS addrs)
// + reversed ti dispatch (long blocks first -> shorter straggler tail).

__global__ __launch_bounds__(256, 2) void k_flash(
    const u16* __restrict__ qw, const u16* __restrict__ qr,
    const u16* __restrict__ kk, const u16* __restrict__ rk,
    const u16* __restrict__ vt, u16* __restrict__ avec) {
  __shared__ __align__(16) u16 Kb[2 * 4096];   // [slot][row j][64] swizzled
  __shared__ __align__(16) u16 Vb[2 * 4096];   // [slot][row d][64] swizzled
  __shared__ __align__(16) u16 BDp[64 * 136];  // [rl][slot(68)][di]
  __shared__ __align__(16) u16 Ps[4 * 1024];   // per-wave 16x64 swizzled
  const int tid = threadIdx.x, lane = tid & 63, w = tid >> 6;
  const int l15 = lane & 15, g = lane >> 4;
  const int bid = blockIdx.x;
  const int work = (bid & 7) * 128 + (bid >> 3);  // XCD swizzle
  const int ti = 15 - (work & 15);                // long (ti=15) first
  const int pair = work >> 4;
  const int n = pair & 15, b = pair >> 4;
  const int i0 = ti * 64;
  const int bn = b * NHH + n;
  const u16* qwb = qw + ((size_t)bn * SEQ + i0) * HDD;
  const u16* qrb = qr + ((size_t)bn * SEQ + i0) * HDD;
  const u16* kbase = kk + (size_t)bn * TOT * HDD;
  const u16* rbase = rk + (size_t)n * TOT * HDD;
  const u16* vbase = vt + (size_t)bn * HDD * TOT;

  bf16x8 qwf[2], qrf[2];
#pragma unroll
  for (int ks = 0; ks < 2; ++ks) {
    int off = (w * 16 + l15) * HDD + ks * 32 + (g << 3);
    qwf[ks] = *(const bf16x8*)(qwb + off);
    qrf[ks] = *(const bf16x8*)(qrb + off);
  }

  const float NEGINF = -__builtin_inff();
  const float C2 = 0.125f * 1.44269504089f;  // scale * log2(e)
  f32x4 oacc[4];
#pragma unroll
  for (int db = 0; db < 4; ++db) oacc[db] = fzero();
  float mrow[4] = {NEGINF, NEGINF, NEGINF, NEGINF};
  float lrow[4] = {0.f, 0.f, 0.f, 0.f};

  const int m0 = 15 - ti;
  const int jtc = ti + 17;

  const int sr = (w << 4) + (lane >> 3);  // staging row
  const int sc = (lane & 7) << 3;         // staging col (u16)

  // ---- precomputed LDS indices (u16 units) ----
  int bd_rd[16], bd_rs[16];
#pragma unroll
  for (int fn = 0; fn < 4; ++fn)
#pragma unroll
    for (int q = 0; q < 4; ++q) {
      int di = (w << 4) + (g << 2) + q;
      int dj = (fn << 4) + l15;
      int rl = (63 + dj - di) & 63;
      int s0 = ((1023 - i0 + dj - di) >> 6) & 1;
      int a0 = rl * 136 + s0 * 68 + di;
      int a1 = rl * 136 + (s0 ^ 1) * 68 + di;
      bd_rd[fn * 4 + q] = a0;
      bd_rs[fn * 4 + q] = a0 + a1;
    }
  int bd_wr[4], bd_ws[4];
  {
    int colw = (w << 4) + (g << 2);
    int sA = m0 & 1;
#pragma unroll
    for (int fn = 0; fn < 4; ++fn) {
      int wl = (fn << 4) + l15;
      int a0 = wl * 136 + sA * 68 + colw;
      int a1 = wl * 136 + (sA ^ 1) * 68 + colw;
      bd_wr[fn] = a0;
      bd_ws[fn] = a0 + a1;
    }
  }
  int ps_wr[16];
#pragma unroll
  for (int fn = 0; fn < 4; ++fn)
#pragma unroll
    for (int q = 0; q < 4; ++q) {
      int row = (g << 2) + q;
      ps_wr[fn * 4 + q] =
          (w << 10) + (row << 6) + ((((fn << 4) + l15)) ^ ((row & 7) << 3));
    }
  const int psr0 = (w << 10) + (l15 << 6) + ((g << 3) ^ ((l15 & 7) << 3));
  const int psr1 = psr0 ^ 32;
  int kr0 = (l15 << 6) + ((g << 3) ^ ((l15 & 7) << 3));  // slot0, ks0
  int kr1 = kr0 ^ 32;
  int vr0 = kr0, vr1 = kr1;
  const int kwb = (sr << 6) + (sc ^ ((sr & 7) << 3));  // slot0 write base

  // global offsets (u16 units), for tile jn = jt+1 / rt = m0+jt+2
  int koff = (64 + sr) * 64 + sc;
  int voff0 = sr * 2048 + 64 + sc;
  int voff1 = voff0 + 8 * 2048;
  int rvo[4];
#pragma unroll
  for (int fn = 0; fn < 4; ++fn)
    rvo[fn] = (((m0 + 2) << 6) + (fn << 4) + l15) * 64 + (g << 3);

  uint4 kg0, kg1, vg0, vg1;
  bf16x8 rfr[8];

  auto bd_comp_store = [&]() {
    f32x4 bd[4];
#pragma unroll
    for (int fn = 0; fn < 4; ++fn) bd[fn] = fzero();
#pragma unroll
    for (int ks = 0; ks < 2; ++ks)
#pragma unroll
      for (int fn = 0; fn < 4; ++fn)
        bd[fn] = mfma16(qrf[ks], rfr[ks * 4 + fn], bd[fn]);
#pragma unroll
    for (int fn = 0; fn < 4; ++fn) {
      ushort4 pk = {bcast(bd[fn][0] * C2), bcast(bd[fn][1] * C2),
                    bcast(bd[fn][2] * C2), bcast(bd[fn][3] * C2)};
      *(ushort4*)(BDp + bd_wr[fn]) = pk;
      bd_wr[fn] = bd_ws[fn] - bd_wr[fn];
    }
  };

  // ---- prologue: stage j-tile 0 (slot0); BD tiles m0, m0+1 ----
  kg0 = *(const uint4*)(kbase + sr * 64 + sc);
  kg1 = *(const uint4*)(kbase + (sr + 8) * 64 + sc);
  vg0 = *(const uint4*)(vbase + sr * 2048 + sc);
  vg1 = *(const uint4*)(vbase + (sr + 8) * 2048 + sc);
#pragma unroll
  for (int fn = 0; fn < 4; ++fn) {
    int ro = ((m0 << 6) + (fn << 4) + l15) * 64 + (g << 3);
#pragma unroll
    for (int ks = 0; ks < 2; ++ks)
      rfr[ks * 4 + fn] = *(const bf16x8*)(rbase + ro + ks * 32);
  }
  bd_comp_store();
#pragma unroll
  for (int fn = 0; fn < 4; ++fn) {
    int ro = (((m0 + 1) << 6) + (fn << 4) + l15) * 64 + (g << 3);
#pragma unroll
    for (int ks = 0; ks < 2; ++ks)
      rfr[ks * 4 + fn] = *(const bf16x8*)(rbase + ro + ks * 32);
  }
  bd_comp_store();
  *(uint4*)(Kb + kwb) = kg0;
  *(uint4*)(Kb + kwb + 512) = kg1;
  *(uint4*)(Vb + kwb) = vg0;
  *(uint4*)(Vb + kwb + 512) = vg1;
  __syncthreads();
  int kw = kwb ^ 4096;  // loop writes slot (jt+1)&1

  for (int jt = 0; jt < jtc; ++jt) {
    const bool haveStage = (jt + 1 < jtc);
    const bool haveBD = (jt + 3 <= jtc);  // rt = m0+jt+2 <= 31
    if (haveStage) {
      kg0 = *(const uint4*)(kbase + koff);
      kg1 = *(const uint4*)(kbase + koff + 512);
      vg0 = *(const uint4*)(vbase + voff0);
      vg1 = *(const uint4*)(vbase + voff1);
    }
    if (haveBD) {
#pragma unroll
      for (int fn = 0; fn < 4; ++fn)
#pragma unroll
        for (int ks = 0; ks < 2; ++ks)
          rfr[ks * 4 + fn] = *(const bf16x8*)(rbase + rvo[fn] + ks * 32);
    }

    // AC from swizzled LDS K
    f32x4 ac[4];
#pragma unroll
    for (int fn = 0; fn < 4; ++fn) ac[fn] = fzero();
#pragma unroll
    for (int fn = 0; fn < 4; ++fn) {
      bf16x8 kf = *(const bf16x8*)(Kb + kr0 + fn * 1024);
      ac[fn] = mfma16(qwf[0], kf, ac[fn]);
    }
#pragma unroll
    for (int fn = 0; fn < 4; ++fn) {
      bf16x8 kf = *(const bf16x8*)(Kb + kr1 + fn * 1024);
      ac[fn] = mfma16(qwf[1], kf, ac[fn]);
    }

    // S = fma(ac, C2, bd_prescaled); mask only on last tile; row max
    const bool last = (jt == jtc - 1);
    float pmax[4] = {NEGINF, NEGINF, NEGINF, NEGINF};
#pragma unroll
    for (int fn = 0; fn < 4; ++fn)
#pragma unroll
      for (int q = 0; q < 4; ++q) {
        float bdv = b2f(BDp[bd_rd[fn * 4 + q]]);
        float sv = __builtin_fmaf(ac[fn][q], C2, bdv);
        if (last) {
          int di = (g << 2) + q;       // w-part cancels: compare dj vs di
          int dj = (fn << 4) + l15 - (w << 4);
          if (dj > di) sv = NEGINF;
        }
        ac[fn][q] = sv;
        pmax[q] = fmaxf(pmax[q], sv);
      }
#pragma unroll
    for (int q = 0; q < 4; ++q) {
#pragma unroll
      for (int off = 1; off < 16; off <<= 1)
        pmax[q] = fmaxf(pmax[q], __shfl_xor(pmax[q], off, 64));
    }
    // defer-max (T13)
    int need = (pmax[0] > mrow[0] + 8.f) | (pmax[1] > mrow[1] + 8.f) |
               (pmax[2] > mrow[2] + 8.f) | (pmax[3] > mrow[3] + 8.f);
    if (__any(need)) {
#pragma unroll
      for (int q = 0; q < 4; ++q) {
        float mn = fmaxf(mrow[q], pmax[q]);
        float sc2 = exp2fast(mrow[q] - mn);
        mrow[q] = mn;
        lrow[q] *= sc2;
#pragma unroll
        for (int db = 0; db < 4; ++db) oacc[db][q] *= sc2;
      }
    }
    // P = exp2(S - m) -> Ps (precomputed swizzled addrs)
#pragma unroll
    for (int fn = 0; fn < 4; ++fn)
#pragma unroll
      for (int q = 0; q < 4; ++q) {
        float p = exp2fast(ac[fn][q] - mrow[q]);
        lrow[q] += p;
        Ps[ps_wr[fn * 4 + q]] = bcast(p);
      }
    // PV from swizzled LDS V
    {
      bf16x8 pa0 = *(const bf16x8*)(Ps + psr0);
      bf16x8 pa1 = *(const bf16x8*)(Ps + psr1);
#pragma unroll
      for (int db = 0; db < 4; ++db) {
        bf16x8 vf = *(const bf16x8*)(Vb + vr0 + db * 1024);
        oacc[db] = mfma16(pa0, vf, oacc[db]);
      }
#pragma unroll
      for (int db = 0; db < 4; ++db) {
        bf16x8 vf = *(const bf16x8*)(Vb + vr1 + db * 1024);
        oacc[db] = mfma16(pa1, vf, oacc[db]);
      }
    }
    // tail: BD(t+2), staged K/V writes, barrier, toggles
    if (haveBD) bd_comp_store();
    if (haveStage) {
      *(uint4*)(Kb + kw) = kg0;
      *(uint4*)(Kb + kw + 512) = kg1;
      *(uint4*)(Vb + kw) = vg0;
      *(uint4*)(Vb + kw + 512) = vg1;
    }
    __syncthreads();
#pragma unroll
    for (int e = 0; e < 16; ++e) bd_rd[e] = bd_rs[e] - bd_rd[e];
    kr0 ^= 4096; kr1 ^= 4096; vr0 ^= 4096; vr1 ^= 4096; kw ^= 4096;
    koff += 4096; voff0 += 64; voff1 += 64;
#pragma unroll
    for (int fn = 0; fn < 4; ++fn) rvo[fn] += 4096;
  }

  // final: row sums, normalize, write avec
#pragma unroll
  for (int q = 0; q < 4; ++q) {
#pragma unroll
    for (int off = 1; off < 16; off <<= 1)
      lrow[q] += __shfl_xor(lrow[q], off, 64);
    lrow[q] = 1.f / lrow[q];
  }
#pragma unroll
  for (int db = 0; db < 4; ++db)
#pragma unroll
    for (int q = 0; q < 4; ++q) {
      int i = i0 + (w << 4) + (g << 2) + q;
      avec[((size_t)i * BB + b) * HH + n * HDD + db * 16 + l15] =
          bcast(oacc[db][q] * lrow[q]);
    }
}

// ------------------------- residual + LayerNorm -------------------------

__global__ __launch_bounds__(256) void k_ln(const float* __restrict__ y,
                                            const float* __restrict__ lw,
                                            const float* __restrict__ lb,
                                            float* __restrict__ out) {
  const int row = blockIdx.x, tid = threadIdx.x;
  const float4 v = *(const float4*)(y + (size_t)row * HH + tid * 4);
  float s = v.x + v.y + v.z + v.w;
  float ss = v.x * v.x + v.y * v.y + v.z * v.z + v.w * v.w;
#pragma unroll
  for (int off = 1; off < 64; off <<= 1) {
    s += __shfl_xor(s, off, 64);
    ss += __shfl_xor(ss, off, 64);
  }
  __shared__ float red[8];
  const int w = tid >> 6, lane = tid & 63;
  if (lane == 0) { red[w] = s; red[4 + w] = ss; }
  __syncthreads();
  float tot = red[0] + red[1] + red[2] + red[3];
  float tss = red[4] + red[5] + red[6] + red[7];
  float mu = tot * (1.f / 1024.f);
  float var = tss * (1.f / 1024.f) - mu * mu;
  float rs = rsqrtf(var + 1e-5f);
  float4 wv = *(const float4*)(lw + tid * 4);
  float4 bv = *(const float4*)(lb + tid * 4);
  float4 o;
  o.x = (v.x - mu) * rs * wv.x + bv.x;
  o.y = (v.y - mu) * rs * wv.y + bv.y;
  o.z = (v.z - mu) * rs * wv.z + bv.z;
  o.w = (v.w - mu) * rs * wv.w + bv.w;
  *(float4*)(out + (size_t)row * HH + tid * 4) = o;
}

// ------------------------- launch -------------------------

extern "C" void kernel_launch(void* const* d_in, const int* in_sizes, int n_in,
                              void* d_out, int out_size, void* d_ws,
                              size_t ws_size, hipStream_t stream) {
  const float* x = (const float*)d_in[0];
  const float* pos = (const float*)d_in[1];
  const float* rwb = (const float*)d_in[2];
  const float* rrb = (const float*)d_in[3];
  // d_in[4] = attn_mask, recomputed analytically
  const float* mem = (const float*)d_in[5];
  const float* wqkv = (const float*)d_in[6];
  const float* wr = (const float*)d_in[7];
  const float* wo = (const float*)d_in[8];
  const float* lnw = (const float*)d_in[9];
  const float* lnb = (const float*)d_in[10];

  char* ws = (char*)d_ws;
  const size_t O_FULL = 0;              // 16,777,216 B (aliased by y later)
  const size_t O_WQKV = 16777216;       // 6,291,456
  const size_t O_WR = 23068672;         // 2,097,152
  const size_t O_WO = 25165824;         // 2,097,152
  const size_t O_POS = 27262976;        // 4,194,304
  const size_t O_QW = 31457280;         // 8,388,608
  const size_t O_QR = 39845888;         // 8,388,608
  const size_t O_K = 48234496;          // 16,777,216
  const size_t O_VT = 65011712;         // 16,777,216
  const size_t O_RK = 81788928;         // 4,194,304
  const size_t O_AVEC = 85983232;       // 8,388,608
  const size_t NEED = 94371840;

  if (ws_size < NEED) return;  // fail visibly

  u16* full = (u16*)(ws + O_FULL);
  u16* wqkv_b = (u16*)(ws + O_WQKV);
  u16* wr_b = (u16*)(ws + O_WR);
  u16* wo_b = (u16*)(ws + O_WO);
  u16* pos_b = (u16*)(ws + O_POS);
  u16* qw = (u16*)(ws + O_QW);
  u16* qr = (u16*)(ws + O_QR);
  u16* kk = (u16*)(ws + O_K);
  u16* vt = (u16*)(ws + O_VT);
  u16* rk = (u16*)(ws + O_RK);
  u16* avec = (u16*)(ws + O_AVEC);
  float* y = (float*)(ws + O_FULL);  // alias: full dead after QKV GEMM

  k_pack<<<8192, 256, 0, stream>>>(mem, x, full);
  k_cvt<<<3072, 256, 0, stream>>>(wqkv, wqkv_b, 786432);
  k_cvt<<<1024, 256, 0, stream>>>(wr, wr_b, 262144);
  k_cvt<<<1024, 256, 0, stream>>>(wo, wo_b, 262144);
  k_cvt<<<2048, 256, 0, stream>>>(pos, pos_b, 524288);

  k_gemm_qkv<<<dim3(64, 24), 256, 0, stream>>>(full, wqkv_b, rwb, rrb, qw, qr,
                                               kk, vt);
  k_gemm_rk<<<dim3(16, 8), 256, 0, stream>>>(pos_b, wr_b, rk);

  k_flash<<<dim3(1024), 256, 0, stream>>>(qw, qr, kk, rk, vt, avec);

  k_gemm_out<<<dim3(32, 8), 256, 0, stream>>>(avec, wo_b, x, y);
  k_ln<<<4096, 256, 0, stream>>>(y, lnw, lnb, (float*)d_out);
}

// Round 8
// 289.670 us; speedup vs baseline: 1.8031x; 1.0375x over previous
//
#include <hip/hip_runtime.h>
#include <stdint.h>

typedef unsigned short u16;
typedef __bf16 bf16t;
typedef bf16t bf16x8 __attribute__((ext_vector_type(8)));
typedef float f32x4 __attribute__((ext_vector_type(4)));

#define DEV static __device__ __forceinline__

DEV u16 f2b(float f) {
  unsigned u = __float_as_uint(f);
  return (u16)((u + 0x7fffu + ((u >> 16) & 1u)) >> 16);
}
DEV u16 bcast(float f) {  // native f32->bf16 (v_cvt, RNE), bit pattern
  union { bf16t b; u16 u; } c;
  c.b = (bf16t)f;
  return c.u;
}
DEV float b2f(u16 h) { return __uint_as_float(((unsigned)h) << 16); }
DEV f32x4 fzero() { f32x4 v = {0.f, 0.f, 0.f, 0.f}; return v; }
DEV f32x4 mfma16(bf16x8 a, bf16x8 b, f32x4 c) {
  return __builtin_amdgcn_mfma_f32_16x16x32_bf16(a, b, c, 0, 0, 0);
}
DEV float exp2fast(float x) { return __builtin_amdgcn_exp2f(x); }  // v_exp_f32
DEV void gload16(const u16* g, u16* l) {  // async global->LDS, 16B/lane
  __builtin_amdgcn_global_load_lds(
      (const __attribute__((address_space(1))) unsigned int*)g,
      (__attribute__((address_space(3))) unsigned int*)l, 16, 0, 0);
}

// Problem constants
#define SEQ 1024
#define MEML 1024
#define BB 4
#define HH 1024
#define NHH 16
#define HDD 64
#define TOT 2048

// ------------------------- elementwise converts -------------------------

__global__ __launch_bounds__(256) void k_pack(const float* __restrict__ mem,
                                              const float* __restrict__ x,
                                              u16* __restrict__ full) {
  size_t id4 = (size_t)blockIdx.x * 256 + threadIdx.x;  // 2,097,152 total
  size_t base = id4 * 4;
  int t = (int)(base >> 12);          // B*H = 4096
  int rem = (int)(base & 4095);
  const float* src = (t < MEML) ? (mem + ((size_t)t << 12) + rem)
                                : (x + ((size_t)(t - MEML) << 12) + rem);
  float4 v = *(const float4*)src;
  ushort4 o;
  o.x = f2b(v.x); o.y = f2b(v.y); o.z = f2b(v.z); o.w = f2b(v.w);
  *(ushort4*)(full + base) = o;
}

// one launch converts wqkv|wr|wo|pos into the CONTIGUOUS ws region
__global__ __launch_bounds__(256) void k_cvt4(const float* __restrict__ s0,
                                              const float* __restrict__ s1,
                                              const float* __restrict__ s2,
                                              const float* __restrict__ s3,
                                              u16* __restrict__ dst) {
  size_t base = ((size_t)blockIdx.x * 256 + threadIdx.x) * 4;  // 7,340,032 tot
  const float* src;
  size_t off;
  if (base < 3145728) { src = s0; off = base; }
  else if (base < 4194304) { src = s1; off = base - 3145728; }
  else if (base < 5242880) { src = s2; off = base - 4194304; }
  else { src = s3; off = base - 5242880; }
  float4 v = *(const float4*)(src + off);
  ushort4 o;
  o.x = f2b(v.x); o.y = f2b(v.y); o.z = f2b(v.z); o.w = f2b(v.w);
  *(ushort4*)(dst + base) = o;
}

// -------------- m97-style bf16 GEMM core (global_load_lds) --------------

template <int MF, int NF>
DEV void gemm_core2(const u16* __restrict__ A, int lda,
                    const u16* __restrict__ Bt, int ldb, int K,
                    f32x4 (&acc)[MF][NF]) {
  __shared__ __align__(16) u16 As[128 * 32];
  __shared__ __align__(16) u16 Bs[128 * 32];
  const int tid = threadIdx.x, lane = tid & 63, wave = tid >> 6;
  const int l15 = lane & 15, g = lane >> 4;
  const int wm = wave >> 1, wn = wave & 1;
#pragma unroll
  for (int fm = 0; fm < MF; ++fm)
#pragma unroll
    for (int fn = 0; fn < NF; ++fn) acc[fm][fn] = fzero();

  const int e8a = tid, e8b = 256 + tid;
  const int ra0 = e8a >> 2, ca0 = (e8a & 3) << 3;
  const int ra1 = e8b >> 2, ca1 = (e8b & 3) << 3;
  u16* asd0 = As + (wave << 9);
  u16* asd1 = As + 2048 + (wave << 9);
  u16* bsd0 = Bs + (wave << 9);
  u16* bsd1 = Bs + 2048 + (wave << 9);

  for (int k0 = 0; k0 < K; k0 += 32) {
    __syncthreads();
    gload16(A + (size_t)ra0 * lda + k0 + ca0, asd0);
    gload16(A + (size_t)ra1 * lda + k0 + ca1, asd1);
    gload16(Bt + (size_t)ra0 * ldb + k0 + ca0, bsd0);
    gload16(Bt + (size_t)ra1 * ldb + k0 + ca1, bsd1);
    __syncthreads();
    bf16x8 af[MF], bfr[NF];
#pragma unroll
    for (int fm = 0; fm < MF; ++fm)
      af[fm] = *(const bf16x8*)(As + ((wm * 64 + fm * 16 + l15) << 5) + (g << 3));
#pragma unroll
    for (int fn = 0; fn < NF; ++fn)
      bfr[fn] = *(const bf16x8*)(Bs + ((wn * 64 + fn * 16 + l15) << 5) + (g << 3));
#pragma unroll
    for (int fm = 0; fm < MF; ++fm)
#pragma unroll
      for (int fn = 0; fn < NF; ++fn)
        acc[fm][fn] = mfma16(af[fm], bfr[fn], acc[fm][fn]);
  }
}

template <int BM, int BN, int MF, int NF, class F>
DEV void epi_apply(f32x4 (&acc)[MF][NF], F&& f) {
  constexpr int WAVES_N = BN / (16 * NF);
  const int lane = threadIdx.x & 63, wave = threadIdx.x >> 6;
  const int wm = wave / WAVES_N, wn = wave % WAVES_N;
#pragma unroll
  for (int fm = 0; fm < MF; ++fm)
#pragma unroll
    for (int fn = 0; fn < NF; ++fn)
#pragma unroll
      for (int q = 0; q < 4; ++q) {
        int rl = wm * (16 * MF) + fm * 16 + ((lane >> 4) << 2) + q;
        int cl = wn * (16 * NF) + fn * 16 + (lane & 15);
        f(rl, cl, acc[fm][fn][q]);
      }
}

// ------------------------- GEMM wrappers -------------------------

__global__ __launch_bounds__(256) void k_gemm_qkv(
    const u16* __restrict__ full, const u16* __restrict__ wqkv,
    const float* __restrict__ rwb, const float* __restrict__ rrb,
    u16* __restrict__ qw, u16* __restrict__ qr, u16* __restrict__ kk,
    u16* __restrict__ vt) {
  f32x4 acc[4][4];
  const u16* A = full + (size_t)blockIdx.x * 128 * 1024;
  const u16* Bt = wqkv + (size_t)blockIdx.y * 128 * 1024;
  gemm_core2<4, 4>(A, 1024, Bt, 1024, 1024, acc);
  const int row0 = blockIdx.x * 128, col0 = blockIdx.y * 128;
  epi_apply<128, 128, 4, 4>(acc, [&](int rl, int cl, float v) {
    int grow = row0 + rl, gcol = col0 + cl;
    int t = grow >> 2, bb = grow & 3;
    int which = gcol >> 10, hd = gcol & 1023;
    int n = hd >> 6, d = hd & 63;
    if (which == 0) {
      if (t >= MEML) {
        int i = t - MEML;
        size_t o = ((size_t)(bb * NHH + n) * SEQ + i) * HDD + d;
        qw[o] = f2b(v + rwb[hd]);
        qr[o] = f2b(v + rrb[hd]);
      }
    } else if (which == 1) {
      kk[((size_t)(bb * NHH + n) * TOT + t) * HDD + d] = f2b(v);
    } else {
      vt[((size_t)(bb * NHH + n) * HDD + d) * TOT + t] = f2b(v);
    }
  });
}

__global__ __launch_bounds__(256) void k_gemm_rk(const u16* __restrict__ pos,
                                                 const u16* __restrict__ wr,
                                                 u16* __restrict__ rk) {
  f32x4 acc[4][4];
  const u16* A = pos + (size_t)blockIdx.x * 128 * 1024;
  const u16* Bt = wr + (size_t)blockIdx.y * 128 * 1024;
  gemm_core2<4, 4>(A, 1024, Bt, 1024, 1024, acc);
  const int row0 = blockIdx.x * 128, col0 = blockIdx.y * 128;
  epi_apply<128, 128, 4, 4>(acc, [&](int rl, int cl, float v) {
    int r = row0 + rl, o = col0 + cl;
    int n = o >> 6, d = o & 63;
    rk[((size_t)n * TOT + r) * HDD + d] = f2b(v);
  });
}

__global__ __launch_bounds__(256) void k_gemm_out(const u16* __restrict__ avec,
                                                  const u16* __restrict__ wo,
                                                  const float* __restrict__ x,
                                                  float* __restrict__ y) {
  f32x4 acc[4][4];
  const u16* A = avec + (size_t)blockIdx.x * 128 * 1024;
  const u16* Bt = wo + (size_t)blockIdx.y * 128 * 1024;
  gemm_core2<4, 4>(A, 1024, Bt, 1024, 1024, acc);
  const int row0 = blockIdx.x * 128, col0 = blockIdx.y * 128;
  epi_apply<128, 128, 4, 4>(acc, [&](int rl, int cl, float v) {
    size_t o = (size_t)(row0 + rl) * HH + (col0 + cl);
    y[o] = v + x[o];
  });
}

// ------------------------- fused flash attention (swapped S layout) ---------
// v7 schedule (1 barrier/iter, staged K/V dbuf, BD ring, loop-carried addrs)
// with SWAPPED QK^T: ac[fn] = mfma(K_frag, Q_frag) -> lane owns row
// i = w*16+l15, 16 j-values (fn*16+(g<<2)+q). Softmax: in-lane max + 2 shfl;
// scalar m/l; P -> Ps as 4 packed ushort4 (chunk-XOR swizzle); PV swapped
// (mfma(V_frag, P_frag)) -> O^T -> 4 packed avec stores. BD producer
// unchanged; only gather-read addresses remapped.

__global__ __launch_bounds__(256, 2) void k_flash(
    const u16* __restrict__ qw, const u16* __restrict__ qr,
    const u16* __restrict__ kk, const u16* __restrict__ rk,
    const u16* __restrict__ vt, u16* __restrict__ avec) {
  __shared__ __align__(16) u16 Kb[2 * 4096];   // [slot][row j][64] swizzled
  __shared__ __align__(16) u16 Vb[2 * 4096];   // [slot][row d][64] swizzled
  __shared__ __align__(16) u16 BDp[64 * 136];  // [rl][slot(68)][di]
  __shared__ __align__(16) u16 Ps[4 * 1024];   // per-wave [16][64], chunk-XOR
  const int tid = threadIdx.x, lane = tid & 63, w = tid >> 6;
  const int l15 = lane & 15, g = lane >> 4;
  const int bid = blockIdx.x;
  const int work = (bid & 7) * 128 + (bid >> 3);  // XCD swizzle
  const int ti = 15 - (work & 15);                // long (ti=15) first
  const int pair = work >> 4;
  const int n = pair & 15, b = pair >> 4;
  const int i0 = ti * 64;
  const int bn = b * NHH + n;
  const u16* qwb = qw + ((size_t)bn * SEQ + i0) * HDD;
  const u16* qrb = qr + ((size_t)bn * SEQ + i0) * HDD;
  const u16* kbase = kk + (size_t)bn * TOT * HDD;
  const u16* rbase = rk + (size_t)n * TOT * HDD;
  const u16* vbase = vt + (size_t)bn * HDD * TOT;

  bf16x8 qwf[2], qrf[2];
#pragma unroll
  for (int ks = 0; ks < 2; ++ks) {
    int off = (w * 16 + l15) * HDD + ks * 32 + (g << 3);
    qwf[ks] = *(const bf16x8*)(qwb + off);
    qrf[ks] = *(const bf16x8*)(qrb + off);
  }

  const float NEGINF = -__builtin_inff();
  const float C2 = 0.125f * 1.44269504089f;  // scale * log2(e)
  f32x4 oacc[4];  // [db][q]: d = db*16+(g<<2)+q, i = w*16+l15
#pragma unroll
  for (int db = 0; db < 4; ++db) oacc[db] = fzero();
  float mrow = NEGINF, lrow = 0.f;

  const int m0 = 15 - ti;
  const int jtc = ti + 17;

  const int sr = (w << 4) + (lane >> 3);  // staging row
  const int sc = (lane & 7) << 3;         // staging col (u16)

  // ---- precomputed LDS indices (u16 units) ----
  const int di = (w << 4) + l15;  // this lane's local row
  int bd_rd[16], bd_rs[16];
#pragma unroll
  for (int fn = 0; fn < 4; ++fn)
#pragma unroll
    for (int q = 0; q < 4; ++q) {
      int dj = (fn << 4) + (g << 2) + q;
      int rl = (63 + dj - di) & 63;
      int s0 = ((1023 - i0 + dj - di) >> 6) & 1;
      int a0 = rl * 136 + s0 * 68 + di;
      int a1 = rl * 136 + (s0 ^ 1) * 68 + di;
      bd_rd[fn * 4 + q] = a0;
      bd_rs[fn * 4 + q] = a0 + a1;
    }
  int bd_wr[4], bd_ws[4];  // producer layout UNCHANGED
  {
    int colw = (w << 4) + (g << 2);
    int sA = m0 & 1;
#pragma unroll
    for (int fn = 0; fn < 4; ++fn) {
      int wl = (fn << 4) + l15;
      int a0 = wl * 136 + sA * 68 + colw;
      int a1 = wl * 136 + (sA ^ 1) * 68 + colw;
      bd_wr[fn] = a0;
      bd_ws[fn] = a0 + a1;
    }
  }
  // Ps: per-wave [16 rows i][64 cols j], chunk(8-u16)-XOR by (l15&3)<<1
  const int psX = (l15 & 3) << 1;
  int ps_w[4];
#pragma unroll
  for (int fn = 0; fn < 4; ++fn)
    ps_w[fn] = (w << 10) + (l15 << 6) + (((fn << 1) + (g >> 1)) ^ psX) * 8 +
               ((g & 1) << 2);
  const int psr0 = (w << 10) + (l15 << 6) + ((g ^ psX) * 8);
  const int psr1 = (w << 10) + (l15 << 6) + (((4 + g) ^ psX) * 8);
  int kr0 = (l15 << 6) + ((g << 3) ^ ((l15 & 7) << 3));  // slot0, ks0
  int kr1 = kr0 ^ 32;
  int vr0 = kr0, vr1 = kr1;
  const int kwb = (sr << 6) + (sc ^ ((sr & 7) << 3));  // slot0 write base

  // global offsets (u16 units), for tile jn = jt+1 / rt = m0+jt+2
  int koff = (64 + sr) * 64 + sc;
  int voff0 = sr * 2048 + 64 + sc;
  int voff1 = voff0 + 8 * 2048;
  int rvo[4];
#pragma unroll
  for (int fn = 0; fn < 4; ++fn)
    rvo[fn] = (((m0 + 2) << 6) + (fn << 4) + l15) * 64 + (g << 3);

  uint4 kg0, kg1, vg0, vg1;
  bf16x8 rfr[8];

  auto bd_comp_store = [&]() {
    f32x4 bd[4];
#pragma unroll
    for (int fn = 0; fn < 4; ++fn) bd[fn] = fzero();
#pragma unroll
    for (int ks = 0; ks < 2; ++ks)
#pragma unroll
      for (int fn = 0; fn < 4; ++fn)
        bd[fn] = mfma16(qrf[ks], rfr[ks * 4 + fn], bd[fn]);
#pragma unroll
    for (int fn = 0; fn < 4; ++fn) {
      ushort4 pk = {bcast(bd[fn][0] * C2), bcast(bd[fn][1] * C2),
                    bcast(bd[fn][2] * C2), bcast(bd[fn][3] * C2)};
      *(ushort4*)(BDp + bd_wr[fn]) = pk;
      bd_wr[fn] = bd_ws[fn] - bd_wr[fn];
    }
  };

  // ---- prologue: stage j-tile 0 (slot0); BD tiles m0, m0+1 ----
  kg0 = *(const uint4*)(kbase + sr * 64 + sc);
  kg1 = *(const uint4*)(kbase + (sr + 8) * 64 + sc);
  vg0 = *(const uint4*)(vbase + sr * 2048 + sc);
  vg1 = *(const uint4*)(vbase + (sr + 8) * 2048 + sc);
#pragma unroll
  for (int fn = 0; fn < 4; ++fn) {
    int ro = ((m0 << 6) + (fn << 4) + l15) * 64 + (g << 3);
#pragma unroll
    for (int ks = 0; ks < 2; ++ks)
      rfr[ks * 4 + fn] = *(const bf16x8*)(rbase + ro + ks * 32);
  }
  bd_comp_store();
#pragma unroll
  for (int fn = 0; fn < 4; ++fn) {
    int ro = (((m0 + 1) << 6) + (fn << 4) + l15) * 64 + (g << 3);
#pragma unroll
    for (int ks = 0; ks < 2; ++ks)
      rfr[ks * 4 + fn] = *(const bf16x8*)(rbase + ro + ks * 32);
  }
  bd_comp_store();
  *(uint4*)(Kb + kwb) = kg0;
  *(uint4*)(Kb + kwb + 512) = kg1;
  *(uint4*)(Vb + kwb) = vg0;
  *(uint4*)(Vb + kwb + 512) = vg1;
  __syncthreads();
  int kw = kwb ^ 4096;  // loop writes slot (jt+1)&1

  for (int jt = 0; jt < jtc; ++jt) {
    const bool haveStage = (jt + 1 < jtc);
    const bool haveBD = (jt + 3 <= jtc);
    if (haveStage) {
      kg0 = *(const uint4*)(kbase + koff);
      kg1 = *(const uint4*)(kbase + koff + 512);
      vg0 = *(const uint4*)(vbase + voff0);
      vg1 = *(const uint4*)(vbase + voff1);
    }
    if (haveBD) {
#pragma unroll
      for (int fn = 0; fn < 4; ++fn)
#pragma unroll
        for (int ks = 0; ks < 2; ++ks)
          rfr[ks * 4 + fn] = *(const bf16x8*)(rbase + rvo[fn] + ks * 32);
    }

    // AC swapped: C[j][i] -> lane row i=di, regs j = fn*16+(g<<2)+q
    f32x4 ac[4];
#pragma unroll
    for (int fn = 0; fn < 4; ++fn) ac[fn] = fzero();
#pragma unroll
    for (int fn = 0; fn < 4; ++fn) {
      bf16x8 kf = *(const bf16x8*)(Kb + kr0 + fn * 1024);
      ac[fn] = mfma16(kf, qwf[0], ac[fn]);
    }
#pragma unroll
    for (int fn = 0; fn < 4; ++fn) {
      bf16x8 kf = *(const bf16x8*)(Kb + kr1 + fn * 1024);
      ac[fn] = mfma16(kf, qwf[1], ac[fn]);
    }

    // S = fma(ac, C2, bd); mask on last tile; in-lane + 2-shfl row max
    const bool last = (jt == jtc - 1);
    float pm = NEGINF;
#pragma unroll
    for (int fn = 0; fn < 4; ++fn)
#pragma unroll
      for (int q = 0; q < 4; ++q) {
        float bdv = b2f(BDp[bd_rd[fn * 4 + q]]);
        float sv = __builtin_fmaf(ac[fn][q], C2, bdv);
        if (last && ((fn << 4) + (g << 2) + q > di)) sv = NEGINF;
        ac[fn][q] = sv;
        pm = fmaxf(pm, sv);
      }
    pm = fmaxf(pm, __shfl_xor(pm, 16, 64));
    pm = fmaxf(pm, __shfl_xor(pm, 32, 64));
    // defer-max (T13)
    if (__any(pm > mrow + 8.f)) {
      float mn = fmaxf(mrow, pm);
      float sc2 = exp2fast(mrow - mn);
      mrow = mn;
      lrow *= sc2;
#pragma unroll
      for (int db = 0; db < 4; ++db)
#pragma unroll
        for (int q = 0; q < 4; ++q) oacc[db][q] *= sc2;
    }
    // P = exp2(S - m) -> Ps (4 packed ushort4, swizzled)
#pragma unroll
    for (int fn = 0; fn < 4; ++fn) {
      float p0 = exp2fast(ac[fn][0] - mrow);
      float p1 = exp2fast(ac[fn][1] - mrow);
      float p2 = exp2fast(ac[fn][2] - mrow);
      float p3 = exp2fast(ac[fn][3] - mrow);
      lrow += (p0 + p1) + (p2 + p3);
      ushort4 pk = {bcast(p0), bcast(p1), bcast(p2), bcast(p3)};
      *(ushort4*)(Ps + ps_w[fn]) = pk;
    }
    // PV swapped: C[d][i]; A = V rows, B = P rows(i)
    {
      bf16x8 pa0 = *(const bf16x8*)(Ps + psr0);
      bf16x8 pa1 = *(const bf16x8*)(Ps + psr1);
#pragma unroll
      for (int db = 0; db < 4; ++db) {
        bf16x8 vf = *(const bf16x8*)(Vb + vr0 + db * 1024);
        oacc[db] = mfma16(vf, pa0, oacc[db]);
      }
#pragma unroll
      for (int db = 0; db < 4; ++db) {
        bf16x8 vf = *(const bf16x8*)(Vb + vr1 + db * 1024);
        oacc[db] = mfma16(vf, pa1, oacc[db]);
      }
    }
    // tail: BD(t+2), staged K/V writes, barrier, toggles
    if (haveBD) bd_comp_store();
    if (haveStage) {
      *(uint4*)(Kb + kw) = kg0;
      *(uint4*)(Kb + kw + 512) = kg1;
      *(uint4*)(Vb + kw) = vg0;
      *(uint4*)(Vb + kw + 512) = vg1;
    }
    __syncthreads();
#pragma unroll
    for (int e = 0; e < 16; ++e) bd_rd[e] = bd_rs[e] - bd_rd[e];
    kr0 ^= 4096; kr1 ^= 4096; vr0 ^= 4096; vr1 ^= 4096; kw ^= 4096;
    koff += 4096; voff0 += 64; voff1 += 64;
#pragma unroll
    for (int fn = 0; fn < 4; ++fn) rvo[fn] += 4096;
  }

  // final: row sum across g-lanes, normalize, packed avec stores
  lrow += __shfl_xor(lrow, 16, 64);
  lrow += __shfl_xor(lrow, 32, 64);
  const float linv = 1.f / lrow;
  const int arow = (i0 + (w << 4) + l15) * BB + b;
  u16* abase = avec + (size_t)arow * HH + n * HDD + (g << 2);
#pragma unroll
  for (int db = 0; db < 4; ++db) {
    ushort4 o = {bcast(oacc[db][0] * linv), bcast(oacc[db][1] * linv),
                 bcast(oacc[db][2] * linv), bcast(oacc[db][3] * linv)};
    *(ushort4*)(abase + db * 16) = o;
  }
}

// ------------------------- residual + LayerNorm -------------------------

__global__ __launch_bounds__(256) void k_ln(const float* __restrict__ y,
                                            const float* __restrict__ lw,
                                            const float* __restrict__ lb,
                                            float* __restrict__ out) {
  const int row = blockIdx.x, tid = threadIdx.x;
  const float4 v = *(const float4*)(y + (size_t)row * HH + tid * 4);
  float s = v.x + v.y + v.z + v.w;
  float ss = v.x * v.x + v.y * v.y + v.z * v.z + v.w * v.w;
#pragma unroll
  for (int off = 1; off < 64; off <<= 1) {
    s += __shfl_xor(s, off, 64);
    ss += __shfl_xor(ss, off, 64);
  }
  __shared__ float red[8];
  const int w = tid >> 6, lane = tid & 63;
  if (lane == 0) { red[w] = s; red[4 + w] = ss; }
  __syncthreads();
  float tot = red[0] + red[1] + red[2] + red[3];
  float tss = red[4] + red[5] + red[6] + red[7];
  float mu = tot * (1.f / 1024.f);
  float var = tss * (1.f / 1024.f) - mu * mu;
  float rs = rsqrtf(var + 1e-5f);
  float4 wv = *(const float4*)(lw + tid * 4);
  float4 bv = *(const float4*)(lb + tid * 4);
  float4 o;
  o.x = (v.x - mu) * rs * wv.x + bv.x;
  o.y = (v.y - mu) * rs * wv.y + bv.y;
  o.z = (v.z - mu) * rs * wv.z + bv.z;
  o.w = (v.w - mu) * rs * wv.w + bv.w;
  *(float4*)(out + (size_t)row * HH + tid * 4) = o;
}

// ------------------------- launch -------------------------

extern "C" void kernel_launch(void* const* d_in, const int* in_sizes, int n_in,
                              void* d_out, int out_size, void* d_ws,
                              size_t ws_size, hipStream_t stream) {
  const float* x = (const float*)d_in[0];
  const float* pos = (const float*)d_in[1];
  const float* rwb = (const float*)d_in[2];
  const float* rrb = (const float*)d_in[3];
  // d_in[4] = attn_mask, recomputed analytically
  const float* mem = (const float*)d_in[5];
  const float* wqkv = (const float*)d_in[6];
  const float* wr = (const float*)d_in[7];
  const float* wo = (const float*)d_in[8];
  const float* lnw = (const float*)d_in[9];
  const float* lnb = (const float*)d_in[10];

  char* ws = (char*)d_ws;
  const size_t O_FULL = 0;              // 16,777,216 B (aliased by y later)
  const size_t O_WQKV = 16777216;       // 6,291,456   } contiguous
  const size_t O_WR = 23068672;         // 2,097,152   } cvt4
  const size_t O_WO = 25165824;         // 2,097,152   } region
  const size_t O_POS = 27262976;        // 4,194,304   }
  const size_t O_QW = 31457280;         // 8,388,608
  const size_t O_QR = 39845888;         // 8,388,608
  const size_t O_K = 48234496;          // 16,777,216
  const size_t O_VT = 65011712;         // 16,777,216
  const size_t O_RK = 81788928;         // 4,194,304
  const size_t O_AVEC = 85983232;       // 8,388,608
  const size_t NEED = 94371840;

  if (ws_size < NEED) return;  // fail visibly

  u16* full = (u16*)(ws + O_FULL);
  u16* wqkv_b = (u16*)(ws + O_WQKV);
  u16* wr_b = (u16*)(ws + O_WR);
  u16* wo_b = (u16*)(ws + O_WO);
  u16* pos_b = (u16*)(ws + O_POS);
  u16* qw = (u16*)(ws + O_QW);
  u16* qr = (u16*)(ws + O_QR);
  u16* kk = (u16*)(ws + O_K);
  u16* vt = (u16*)(ws + O_VT);
  u16* rk = (u16*)(ws + O_RK);
  u16* avec = (u16*)(ws + O_AVEC);
  float* y = (float*)(ws + O_FULL);  // alias: full dead after QKV GEMM

  k_pack<<<8192, 256, 0, stream>>>(mem, x, full);
  k_cvt4<<<7168, 256, 0, stream>>>(wqkv, wr, wo, pos, wqkv_b);

  k_gemm_qkv<<<dim3(64, 24), 256, 0, stream>>>(full, wqkv_b, rwb, rrb, qw, qr,
                                               kk, vt);
  k_gemm_rk<<<dim3(16, 8), 256, 0, stream>>>(pos_b, wr_b, rk);

  k_flash<<<dim3(1024), 256, 0, stream>>>(qw, qr, kk, rk, vt, avec);

  k_gemm_out<<<dim3(32, 8), 256, 0, stream>>>(avec, wo_b, x, y);
  k_ln<<<4096, 256, 0, stream>>>(y, lnw, lnb, (float*)d_out);
}